// Round 7
// baseline (613.759 us; speedup 1.0000x reference)
//
#include <hip/hip_runtime.h>
#include <cstdint>
#include <cstddef>

typedef __bf16 bf16;
typedef __bf16 bf16x4 __attribute__((ext_vector_type(4)));
typedef __bf16 bf16x8 __attribute__((ext_vector_type(8)));
typedef float  fx4    __attribute__((ext_vector_type(4)));

// Problem dims (fixed): B=4, S=2048, D=1024, H=8, E=4, DH=128, K_route=2

// async global->LDS DMA, 16 B per lane; dest = wave-uniform base + lane*16 (m97/m104)
__device__ __forceinline__ void async16(const void* g, void* l) {
  __builtin_amdgcn_global_load_lds((const __attribute__((address_space(1))) void*)g,
                                   (__attribute__((address_space(3))) void*)l, 16, 0, 0);
}

#define BARRIER() do { asm volatile("" ::: "memory"); __builtin_amdgcn_s_barrier(); \
                       asm volatile("" ::: "memory"); } while (0)

// DPP row-rotate (within 16-lane rows) — VALU-pipe cross-lane reduce (vs ds_bpermute).
template <int CTRL>
__device__ __forceinline__ float dppf(float x) {
  return __int_as_float(__builtin_amdgcn_update_dpp(
      0, __float_as_int(x), CTRL, 0xf, 0xf, true));
}

// vectorized f32 -> bf16 (G13: 16B/lane loads), n4 = n/4
__global__ __launch_bounds__(256) void f32_to_bf16(const float4* __restrict__ src,
                                                   bf16x4* __restrict__ dst, int n4) {
  int i = blockIdx.x * 256 + threadIdx.x;
  if (i < n4) {
    float4 v = src[i];
    bf16x4 o;
    o[0] = (bf16)v.x; o[1] = (bf16)v.y; o[2] = (bf16)v.z; o[3] = (bf16)v.w;
    dst[i] = o;
  }
}

// wvt[h][dh][e][k] <- v_w[h][e][k][dh]; LDS-tiled 64x64 transpose, coalesced both sides.
__global__ __launch_bounds__(256) void make_wvt(const float* __restrict__ v_w,
                                                bf16* __restrict__ wvt) {
  __shared__ float tile[64][65];
  const int he = blockIdx.z, k0 = blockIdx.x * 64, dh0 = blockIdx.y * 64;
  const float* in = v_w + (size_t)he * 1024 * 128;
  #pragma unroll
  for (int j = 0; j < 16; j++) {
    int idx = threadIdx.x + j * 256;
    int r = idx >> 6, c = idx & 63;                 // r=k, c=dh
    tile[r][c] = in[(size_t)(k0 + r) * 128 + dh0 + c];
  }
  __syncthreads();
  const int h = he >> 2, e = he & 3;
  bf16* outp = wvt + ((size_t)(h * 128 + dh0) * 4 + e) * 1024 + k0;
  #pragma unroll
  for (int j = 0; j < 16; j++) {
    int idx = threadIdx.x + j * 256;
    int r = idx >> 6, c = idx & 63;                 // r=dh, c=k
    outp[(size_t)r * 4096 + c] = (bf16)tile[c][r];
  }
}

// wot[d][h][e][dh] <- o_w[h][e][dh][d]
__global__ __launch_bounds__(256) void make_wot(const float* __restrict__ o_w,
                                                bf16* __restrict__ wot) {
  __shared__ float tile[64][65];
  const int he = blockIdx.z, d0 = blockIdx.x * 64, dh0 = blockIdx.y * 64;
  const float* in = o_w + (size_t)he * 128 * 1024;
  #pragma unroll
  for (int j = 0; j < 16; j++) {
    int idx = threadIdx.x + j * 256;
    int r = idx >> 6, c = idx & 63;                 // r=dh, c=d
    tile[r][c] = in[(size_t)(dh0 + r) * 1024 + d0 + c];
  }
  __syncthreads();
  bf16* outp = wot + (size_t)d0 * 4096 + he * 128 + dh0;
  #pragma unroll
  for (int j = 0; j < 16; j++) {
    int idx = threadIdx.x + j * 256;
    int r = idx >> 6, c = idx & 63;                 // r=d, c=dh
    outp[(size_t)r * 4096 + c] = (bf16)tile[c][r];
  }
}

// ---------------- gating (R6): register-blocked LDS-staged mini-GEMM ----------------
__global__ __launch_bounds__(256) void gating(const float* __restrict__ q_src,
                                              const float* __restrict__ k_src,
                                              const float* __restrict__ sel_v_w,
                                              const float* __restrict__ sel_o_w,
                                              const float* __restrict__ bias_v,
                                              const float* __restrict__ bias_o,
                                              float* __restrict__ gate_v,
                                              float* __restrict__ gate_o,
                                              float* __restrict__ d_out) {
  const int g = blockIdx.y;
  const int m0 = blockIdx.x * 64;
  const float* x = g ? q_src : k_src;
  const float* w = g ? sel_o_w : sel_v_w;
  const float* bias = g ? bias_o : bias_v;
  float* gate = g ? gate_o : gate_v;
  float* idxo = d_out + 8388608 + g * 131072;       // v_idx then o_idx, as float values

  // [buf][ xs 64x128 f32 | ws 32x128 f32 ] = 2 x 48 KB
  __shared__ __align__(16) float smem[2 * 12288];

  const int t = threadIdx.x;
  const int hg = t & 7;          // head
  const int tg = t >> 3;         // token pair 0..31

  auto stage = [&](int buf, int k0) {
    float* xs = smem + buf * 12288;
    float* ws = xs + 8192;
    #pragma unroll
    for (int p = 0; p < 8; p++) {                    // xs: 64 rows x 128 f32
      int of = p * 1024 + t * 4;
      int row = of >> 7, c = (of >> 2) & 31;
      int sc = c ^ ((row >> 1) & 7);                 // pre-swizzled source chunk
      async16(x + (size_t)(m0 + row) * 1024 + k0 + sc * 4, xs + of);
    }
    #pragma unroll
    for (int p = 0; p < 4; p++) {                    // ws: 32 rows x 128 f32
      int of = p * 1024 + t * 4;
      int row = of >> 7, c = (of >> 2) & 31;
      int sc = c ^ ((row >> 2) & 7);
      async16(w + (size_t)row * 1024 + k0 + sc * 4, ws + of);
    }
  };

  double acc[2][4] = {};

  stage(0, 0);
  int buf = 0;
  for (int c8 = 0; c8 < 8; c8++) {
    if (c8 < 7) {
      stage(buf ^ 1, (c8 + 1) * 128);                  // prefetch next chunk
      asm volatile("s_waitcnt vmcnt(12)" ::: "memory"); // wait current chunk only
    } else {
      asm volatile("s_waitcnt vmcnt(0)" ::: "memory");
    }
    BARRIER();
    const float* xs = smem + buf * 12288;
    const float* ws = xs + 8192;
    const int xr0 = tg * 2;
    #pragma unroll 4
    for (int k4 = 0; k4 < 32; k4++) {
      float4 x0 = *(const float4*)(xs + (size_t)xr0 * 128 + (size_t)((k4 ^ (tg & 7)) * 4));
      float4 x1 = *(const float4*)(xs + (size_t)(xr0 + 1) * 128 + (size_t)((k4 ^ (tg & 7)) * 4));
      double x0d[4] = {(double)x0.x, (double)x0.y, (double)x0.z, (double)x0.w};
      double x1d[4] = {(double)x1.x, (double)x1.y, (double)x1.z, (double)x1.w};
      #pragma unroll
      for (int e = 0; e < 4; e++) {
        int wr = hg * 4 + e;
        float4 wv = *(const float4*)(ws + (size_t)wr * 128 + (size_t)((k4 ^ hg) * 4));
        double w0 = (double)wv.x, w1 = (double)wv.y, w2 = (double)wv.z, w3 = (double)wv.w;
        acc[0][e] += x0d[0] * w0 + x0d[1] * w1 + x0d[2] * w2 + x0d[3] * w3;
        acc[1][e] += x1d[0] * w0 + x1d[1] * w1 + x1d[2] * w2 + x1d[3] * w3;
      }
    }
    BARRIER();   // all waves done with buf before it is re-staged next iteration
    buf ^= 1;
  }

  const float log2e = 1.4426950408889634f;
  float b0 = bias[0], b1 = bias[1], b2 = bias[2], b3 = bias[3];
  #pragma unroll
  for (int tok = 0; tok < 2; tok++) {
    int m = m0 + tg * 2 + tok;
    float sel[4];
    #pragma unroll
    for (int e = 0; e < 4; e++) {
      float lv = (float)acc[tok][e];
      sel[e] = 1.0f / (1.0f + __builtin_amdgcn_exp2f(-lv * log2e));
    }
    float vb[4] = {sel[0] + b0, sel[1] + b1, sel[2] + b2, sel[3] + b3};
    int i0 = 0;
    #pragma unroll
    for (int e = 1; e < 4; e++) if (vb[e] > vb[i0]) i0 = e;
    int i1 = -1; float best = -1e30f;
    #pragma unroll
    for (int e = 0; e < 4; e++) { if (e == i0) continue; if (vb[e] > best) { best = vb[e]; i1 = e; } }
    float4 gv;
    gv.x = (i0 == 0 || i1 == 0) ? sel[0] : 0.f;
    gv.y = (i0 == 1 || i1 == 1) ? sel[1] : 0.f;
    gv.z = (i0 == 2 || i1 == 2) ? sel[2] : 0.f;
    gv.w = (i0 == 3 || i1 == 3) ? sel[3] : 0.f;
    *(float4*)(gate + ((size_t)m * 8 + hg) * 4) = gv;
    idxo[m * 16 + hg * 2 + 0] = (float)i0;
    idxo[m * 16 + hg * 2 + 1] = (float)i1;
  }
}

// expander: Ae[m][(h*4+e)*128+dh] = outb[m][h*128+dh] * gate_o[m][h][e]
__global__ __launch_bounds__(256) void expand_o(const bf16* __restrict__ outb,
                                                const float* __restrict__ gate_o,
                                                bf16* __restrict__ Ae) {
  int idx = blockIdx.x * 256 + threadIdx.x;   // unit = 8 bf16
  int m = idx >> 9;                           // 512 units per row
  int u = idx & 511;
  int he = u >> 4;                            // h*4+e
  int hh = he >> 2, e = he & 3;
  int dh0 = (u & 15) * 8;
  float gv = gate_o[((size_t)m * 8 + hh) * 4 + e];
  bf16x8 v = *(const bf16x8*)(outb + ((size_t)m * 8 + hh) * 128 + dh0);
  #pragma unroll
  for (int j = 0; j < 8; j++) v[j] = (bf16)((float)v[j] * gv);
  *(bf16x8*)(Ae + (size_t)m * 4096 + u * 8) = v;
}

// ---------------- GEMM: C[M x N] = A @ BT^T, bf16 MFMA 16x16x32 ----------------
// R5: 256x128 tile, 8 waves (512 thr), BK=64, double-buffered 96 KB LDS -> 1 block/CU,
// grid exactly 256. Per K-step: stage next tile, counted vmcnt(6), 4 phases of
// {ds_read subtile -> barrier -> setprio(1) -> MFMA -> setprio(0) -> barrier}.
// T2 16B-chunk XOR swizzle (R4: conflicts 2.5e7 -> 1.3e5). bid&7 = N-panel / head (T1).
template <int MODE>
__global__ __launch_bounds__(512) void gemm_moe(const bf16* __restrict__ Abf,
                                                const bf16* __restrict__ BT,
                                                const float* __restrict__ gate,
                                                bf16* __restrict__ Cbf,
                                                float* __restrict__ Cf32,
                                                float scale) {
  constexpr int KDIM = (MODE == 0) ? 1024 : 4096;
  constexpr int ASTRIDE = (MODE == 2) ? 4096 : 1024;
  // [2][A 256x64] at 0, [2][B 128x64] at 32768 (bf16 units): 96 KB total
  __shared__ __align__(16) bf16 smem[49152];
  const int t = threadIdx.x;
  const int wave = t >> 6, lane = t & 63;
  const int wr = wave >> 1, wc = wave & 1;          // 4 M-groups x 2 N-groups
  const int quad = lane >> 4, l16 = lane & 15;
  const int bid = blockIdx.x;
  const int m0 = (bid >> 3) * 256;
  const int n0 = (MODE == 1) ? 0 : (bid & 7) * 128;
  const int h = (MODE == 1) ? (bid & 7) : 0;
  const bf16* BTh = (MODE == 1) ? BT + (size_t)h * 128 * 4096 : BT;

  fx4 acc[4][4] = {};    // per-wave 64x64 output (4 mi x 4 ni)
  fx4 accT[4][4] = {};   // gated total (mode 1 only; DCE'd otherwise)

  const int srow = t >> 3, sch = t & 7;   // staging: 64 rows x 8 chunks (16 B) per pass

  auto stage = [&](int buf, int k0) {
    bf16* As = smem + buf * 16384;
    bf16* Bs = smem + 32768 + buf * 8192;
    #pragma unroll
    for (int p = 0; p < 2; p++) {                    // B: 128 rows
      int row = p * 64 + srow;
      int sc = sch ^ (row & 7);
      async16(BTh + (size_t)(n0 + row) * KDIM + k0 + sc * 8,
              Bs + row * 64 + sch * 8);
    }
    int col = (MODE == 1) ? (k0 & 1023) : k0;
    #pragma unroll
    for (int p = 0; p < 4; p++) {                    // A: 256 rows
      int row = p * 64 + srow;
      int sc = sch ^ (row & 7);
      async16(Abf + (size_t)(m0 + row) * ASTRIDE + col + sc * 8,
              As + row * 64 + sch * 8);
    }
  };

  stage(0, 0);
  int buf = 0;
  for (int k0 = 0; k0 < KDIM; k0 += 64) {
    if (k0 + 64 < KDIM) {
      stage(buf ^ 1, k0 + 64);                         // prefetch next K-tile
      asm volatile("s_waitcnt vmcnt(6)" ::: "memory"); // wait current tile only
    } else {
      asm volatile("s_waitcnt vmcnt(0)" ::: "memory");
    }
    BARRIER();
    const bf16* As = smem + buf * 16384;
    const bf16* Bs = smem + 32768 + buf * 8192;
    #pragma unroll
    for (int kk = 0; kk < 64; kk += 32) {
      bf16x8 af[4], bfr[4];
      // phase A: A-frags + B-frags ni 0,1
      #pragma unroll
      for (int i = 0; i < 4; i++) {
        int ar = wr * 64 + i * 16 + l16;
        af[i] = *(const bf16x8*)(As + ar * 64 + ((((kk >> 3) + quad) ^ (ar & 7)) * 8));
      }
      #pragma unroll
      for (int i = 0; i < 2; i++) {
        int br = wc * 64 + i * 16 + l16;
        bfr[i] = *(const bf16x8*)(Bs + br * 64 + ((((kk >> 3) + quad) ^ (br & 7)) * 8));
      }
      BARRIER();
      __builtin_amdgcn_s_setprio(1);
      #pragma unroll
      for (int mi = 0; mi < 4; mi++)
        #pragma unroll
        for (int ni = 0; ni < 2; ni++)
          acc[mi][ni] = __builtin_amdgcn_mfma_f32_16x16x32_bf16(af[mi], bfr[ni], acc[mi][ni], 0, 0, 0);
      __builtin_amdgcn_s_setprio(0);
      BARRIER();
      // phase B: B-frags ni 2,3 (af held in regs)
      #pragma unroll
      for (int i = 2; i < 4; i++) {
        int br = wc * 64 + i * 16 + l16;
        bfr[i] = *(const bf16x8*)(Bs + br * 64 + ((((kk >> 3) + quad) ^ (br & 7)) * 8));
      }
      BARRIER();
      __builtin_amdgcn_s_setprio(1);
      #pragma unroll
      for (int mi = 0; mi < 4; mi++)
        #pragma unroll
        for (int ni = 2; ni < 4; ni++)
          acc[mi][ni] = __builtin_amdgcn_mfma_f32_16x16x32_bf16(af[mi], bfr[ni], acc[mi][ni], 0, 0, 0);
      __builtin_amdgcn_s_setprio(0);
      BARRIER();
    }
    if constexpr (MODE == 1) {
      if (((k0 + 64) & 1023) == 0) {     // expert-chunk boundary: 4 merges total
        const int e = k0 >> 10;
        #pragma unroll
        for (int mi = 0; mi < 4; mi++)
          #pragma unroll
          for (int r = 0; r < 4; r++) {
            int m = m0 + wr * 64 + mi * 16 + quad * 4 + r;
            float gv = gate[((size_t)m * 8 + h) * 4 + e];
            #pragma unroll
            for (int ni = 0; ni < 4; ni++)
              accT[mi][ni][r] += gv * acc[mi][ni][r];
          }
        #pragma unroll
        for (int mi = 0; mi < 4; mi++)
          #pragma unroll
          for (int ni = 0; ni < 4; ni++)
            #pragma unroll
            for (int j = 0; j < 4; j++) acc[mi][ni][j] = 0.f;
      }
    }
    buf ^= 1;
  }

  if (MODE == 1) {
    // transpose through LDS -> vbT[b,h,dh,s] with coalesced global writes
    #pragma unroll
    for (int mi = 0; mi < 4; mi++)
      #pragma unroll
      for (int ni = 0; ni < 4; ni++) {
        int nl = wc * 64 + ni * 16 + l16;
        int ml = wr * 64 + mi * 16 + quad * 4;
        bf16x4 pk;
        #pragma unroll
        for (int r = 0; r < 4; r++) pk[r] = (bf16)accT[mi][ni][r];
        *(bf16x4*)(smem + nl * 264 + ml) = pk;
      }
    __syncthreads();
    int b = m0 >> 11, s0 = m0 & 2047;
    const int row = t >> 2, seg = t & 3;
    bf16* dst = Cbf + (((size_t)(b * 8 + h) * 128) + row) * 2048 + s0 + seg * 64;
    #pragma unroll
    for (int j = 0; j < 8; j++)
      *(float4*)(dst + j * 8) = *(float4*)(smem + row * 264 + seg * 64 + j * 8);
    return;
  }

  // epilogue: C/D layout col=lane&15, row=quad*4+reg
  #pragma unroll
  for (int mi = 0; mi < 4; mi++)
    #pragma unroll
    for (int ni = 0; ni < 4; ni++)
      #pragma unroll
      for (int r = 0; r < 4; r++) {
        int m = m0 + wr * 64 + mi * 16 + quad * 4 + r;
        int n = n0 + wc * 64 + ni * 16 + l16;
        float v = acc[mi][ni][r] * scale;
        if (MODE == 0) {
          int b = m >> 11, s = m & 2047, hh = n >> 7, dh = n & 127;
          Cbf[(((size_t)(b * 8 + hh) * 2048 + s) << 7) + dh] = (bf16)v;
        } else {
          Cf32[(size_t)m * 1024 + n] = v;
        }
      }
}

// ---------------- flash attention (causal) ----------------
// R7: 2 waves x 32 q-rows each (128 threads). Rationale: R6 counters showed VALU 41% +
// LDS-pipe ~43% co-bound; all 4 waves read IDENTICAL K/V fragments (K/V shared, only Q
// differs). With 32 q-rows/wave each kf/vf read feeds 2 MFMAs -> b128 instr per unit work
// -47%. Softmax gets 8 independent row-chains/wave (ILP replaces lost TLP at 1 wave/SIMD).
// Same 64-row q-tiles, same pairing (pass qt = 31-x then x, 33 iters/block), 512 blocks =
// 2/CU. XCD-clustered bh remap (T1): 16 blocks sharing (b,h) land on one XCD (R6 FETCH
// was 194 MB vs ~33 MB unique = 6x cross-XCD duplication).
__global__ __launch_bounds__(128) void attn_kernel(const bf16* __restrict__ qb,
                                                   const bf16* __restrict__ kb,
                                                   const bf16* __restrict__ vbT,
                                                   bf16* __restrict__ outb) {
  // XCD-clustering remap: linear = y*16+x; bh = (linear%8)*4 + (linear>>3)%4 keeps all
  // 16 pair-indices of one bh on one XCD (assuming XCD = dispatch_id % 8).
  const int linear = blockIdx.y * 16 + blockIdx.x;
  const int bh = (linear & 7) * 4 + ((linear >> 3) & 3);
  const int px = linear >> 5;                      // pair index 0..15
  const int b = bh >> 3, h = bh & 7;
  __shared__ __align__(16) bf16 Ks[2][64 * 128];    // [buf][k-row * 128 + dh], swizzled
  __shared__ __align__(16) bf16 VTs[2][128 * 64];   // [buf][dh-row * 64 + s], swizzled
  __shared__ __align__(16) bf16 Ps[2][32][72];
  const int t = threadIdx.x, wave = t >> 6, lane = t & 63;
  const int quad = lane >> 4, l16 = lane & 15;
  const bf16* qbase  = qb  + (size_t)bh * 2048 * 128;
  const bf16* kbase  = kb  + (size_t)bh * 2048 * 128;
  const bf16* vtbase = vbT + (size_t)bh * 128 * 2048;

  auto stage = [&](int buf, int kt) {
    #pragma unroll
    for (int p = 0; p < 8; p++) {
      int o = p * 2048 + t * 16;                         // byte offset in 16 KiB tile
      int kr = o >> 8, kc = o & 255;                     // 256 B rows (128 bf16)
      async16((const char*)kbase + (size_t)(kt * 64 + kr) * 256 + (kc ^ ((kr & 7) << 4)),
              (char*)&Ks[buf][0] + o);
    }
    #pragma unroll
    for (int p = 0; p < 8; p++) {
      int o = p * 2048 + t * 16;
      int vr = o >> 7, vc = o & 127;                     // 128 B rows (64 bf16)
      async16((const char*)vtbase + (size_t)vr * 4096 + kt * 128 + (vc ^ ((vr & 7) << 4)),
              (char*)&VTs[buf][0] + o);
    }
  };

  #pragma unroll 1
  for (int pass = 0; pass < 2; pass++) {
    const int qt = pass ? px : (31 - px);                // heavy tile first

    bf16x8 qf[2][4];
    #pragma unroll
    for (int g = 0; g < 2; g++)
      #pragma unroll
      for (int dk = 0; dk < 4; dk++)
        qf[g][dk] = *(const bf16x8*)(qbase +
            (size_t)(qt * 64 + wave * 32 + g * 16 + l16) * 128 + dk * 32 + quad * 8);

    float m_run[2][4], l_run[2][4];
    fx4 acc_o[2][8] = {};
    #pragma unroll
    for (int g = 0; g < 2; g++)
      #pragma unroll
      for (int r = 0; r < 4; r++) { m_run[g][r] = -1e30f; l_run[g][r] = 0.f; }

    stage(0, 0);
    int cur = 0;

    for (int kt = 0; kt <= qt; kt++) {
      if (kt < qt) {
        stage(cur ^ 1, kt + 1);                            // prefetch next tile
        asm volatile("s_waitcnt vmcnt(16)" ::: "memory");  // wait tile kt only
      } else {
        asm volatile("s_waitcnt vmcnt(0)" ::: "memory");
      }
      __builtin_amdgcn_s_barrier();
      asm volatile("" ::: "memory");

      const char* Ksb  = (const char*)&Ks[cur][0];
      const char* VTsb = (const char*)&VTs[cur][0];

      fx4 accs[2][4] = {};
      __builtin_amdgcn_s_setprio(1);
      #pragma unroll
      for (int ni = 0; ni < 4; ni++)
        #pragma unroll
        for (int dk = 0; dk < 4; dk++) {
          int r = ni * 16 + l16;
          bf16x8 kf = *(const bf16x8*)(Ksb + r * 256 + ((dk * 64 + quad * 16) ^ ((r & 7) << 4)));
          accs[0][ni] = __builtin_amdgcn_mfma_f32_16x16x32_bf16(qf[0][dk], kf, accs[0][ni], 0, 0, 0);
          accs[1][ni] = __builtin_amdgcn_mfma_f32_16x16x32_bf16(qf[1][dk], kf, accs[1][ni], 0, 0, 0);
        }
      __builtin_amdgcn_s_setprio(0);

      if (kt == qt) {   // causal mask on the diagonal tile
        #pragma unroll
        for (int g = 0; g < 2; g++)
          #pragma unroll
          for (int ni = 0; ni < 4; ni++)
            #pragma unroll
            for (int r = 0; r < 4; r++) {
              int qr = wave * 32 + g * 16 + quad * 4 + r;
              int kc = ni * 16 + l16;
              if (kc > qr) accs[g][ni][r] = -1e30f;
            }
      }

      // softmax in exp2 domain (log2e folded into Q scale); DPP row_ror reductions.
      // 8 independent row chains per wave -> ILP hides DPP/exp latency at 1 wave/SIMD.
      #pragma unroll
      for (int g = 0; g < 2; g++)
        #pragma unroll
        for (int r = 0; r < 4; r++) {
          float mx = fmaxf(fmaxf(accs[g][0][r], accs[g][1][r]),
                           fmaxf(accs[g][2][r], accs[g][3][r]));
          mx = fmaxf(mx, dppf<0x121>(mx));   // row_ror:1
          mx = fmaxf(mx, dppf<0x122>(mx));   // row_ror:2
          mx = fmaxf(mx, dppf<0x124>(mx));   // row_ror:4
          mx = fmaxf(mx, dppf<0x128>(mx));   // row_ror:8
          float m_new = fmaxf(m_run[g][r], mx);
          float alpha = __builtin_amdgcn_exp2f(m_run[g][r] - m_new);
          float rs = 0.f;
          #pragma unroll
          for (int ni = 0; ni < 4; ni++) {
            float p = __builtin_amdgcn_exp2f(accs[g][ni][r] - m_new);
            accs[g][ni][r] = p; rs += p;
          }
          rs += dppf<0x121>(rs);
          rs += dppf<0x122>(rs);
          rs += dppf<0x124>(rs);
          rs += dppf<0x128>(rs);
          l_run[g][r] = l_run[g][r] * alpha + rs;
          m_run[g][r] = m_new;
          #pragma unroll
          for (int nj = 0; nj < 8; nj++) acc_o[g][nj][r] *= alpha;
        }

      // P: C-layout -> LDS -> A-layout (per-wave region; DS in-order within a wave)
      #pragma unroll
      for (int g = 0; g < 2; g++)
        #pragma unroll
        for (int ni = 0; ni < 4; ni++)
          #pragma unroll
          for (int r = 0; r < 4; r++)
            Ps[wave][g * 16 + quad * 4 + r][ni * 16 + l16] = (bf16)accs[g][ni][r];

      __builtin_amdgcn_s_setprio(1);
      #pragma unroll
      for (int step = 0; step < 2; step++) {
        bf16x8 pf0 = *(const bf16x8*)&Ps[wave][l16][step * 32 + quad * 8];
        bf16x8 pf1 = *(const bf16x8*)&Ps[wave][16 + l16][step * 32 + quad * 8];
        #pragma unroll
        for (int nj = 0; nj < 8; nj++) {
          int r = nj * 16 + l16;
          bf16x8 vf = *(const bf16x8*)(VTsb + r * 128 + ((step * 64 + quad * 16) ^ ((r & 7) << 4)));
          acc_o[0][nj] = __builtin_amdgcn_mfma_f32_16x16x32_bf16(pf0, vf, acc_o[0][nj], 0, 0, 0);
          acc_o[1][nj] = __builtin_amdgcn_mfma_f32_16x16x32_bf16(pf1, vf, acc_o[1][nj], 0, 0, 0);
        }
      }
      __builtin_amdgcn_s_setprio(0);

      asm volatile("" ::: "memory");
      __builtin_amdgcn_s_barrier();   // all waves done reading buf[cur] before re-stage
      cur ^= 1;
    }

    #pragma unroll
    for (int g = 0; g < 2; g++)
      #pragma unroll
      for (int nj = 0; nj < 8; nj++)
        #pragma unroll
        for (int r = 0; r < 4; r++) {
          int s = qt * 64 + wave * 32 + g * 16 + quad * 4 + r;
          int token = b * 2048 + s;
          float o = acc_o[g][nj][r] / l_run[g][r];
          outb[((size_t)token * 8 + h) * 128 + nj * 16 + l16] = (bf16)o;
        }
  }
}

// ---------------- launch ----------------
extern "C" void kernel_launch(void* const* d_in, const int* in_sizes, int n_in,
                              void* d_out, int out_size, void* d_ws, size_t ws_size,
                              hipStream_t stream) {
  const float* q_src  = (const float*)d_in[0];
  const float* k_src  = (const float*)d_in[1];
  const float* v_src  = (const float*)d_in[2];
  const float* wq     = (const float*)d_in[3];
  const float* wk     = (const float*)d_in[4];
  const float* sel_v_w = (const float*)d_in[5];
  const float* sel_o_w = (const float*)d_in[6];
  const float* v_w    = (const float*)d_in[7];
  const float* o_w    = (const float*)d_in[8];
  const float* bias_v = (const float*)d_in[9];
  const float* bias_o = (const float*)d_in[10];
  float* out = (float*)d_out;

  char* ws = (char*)d_ws;
  size_t off = 0;
  auto alloc = [&](size_t bytes) { char* p = ws + off; off += (bytes + 255) & ~(size_t)255; return p; };
  bf16* wqb   = (bf16*)alloc((size_t)1024 * 1024 * 2);
  bf16* wkb   = (bf16*)alloc((size_t)1024 * 1024 * 2);
  bf16* wvt   = (bf16*)alloc((size_t)8 * 128 * 4 * 1024 * 2);
  bf16* wot   = (bf16*)alloc((size_t)1024 * 4096 * 2);
  float* gate_v = (float*)alloc((size_t)8192 * 32 * 4);
  float* gate_o = (float*)alloc((size_t)8192 * 32 * 4);
  bf16* qsb   = (bf16*)alloc((size_t)8192 * 1024 * 2);   // bf16 copies of srcs
  bf16* ksb   = (bf16*)alloc((size_t)8192 * 1024 * 2);
  bf16* vsb   = (bf16*)alloc((size_t)8192 * 1024 * 2);
  bf16* qb    = (bf16*)alloc((size_t)8192 * 1024 * 2);   // [b,h,s,dh]
  bf16* kb    = (bf16*)alloc((size_t)8192 * 1024 * 2);   // [b,h,s,dh]
  bf16* vbT   = (bf16*)alloc((size_t)8192 * 1024 * 2);   // [b,h,dh,s]
  bf16* outb  = (bf16*)alloc((size_t)8192 * 1024 * 2);   // [b,s,h,dh]
  // Ae (8192x4096 bf16 = 64 MB) overlays qsb..qb, all dead by the time expand_o runs
  bf16* Ae    = qsb;

  f32_to_bf16<<<1024, 256, 0, stream>>>((const float4*)wq, (bf16x4*)wqb, 262144);
  f32_to_bf16<<<1024, 256, 0, stream>>>((const float4*)wk, (bf16x4*)wkb, 262144);
  f32_to_bf16<<<8192, 256, 0, stream>>>((const float4*)q_src, (bf16x4*)qsb, 2097152);
  f32_to_bf16<<<8192, 256, 0, stream>>>((const float4*)k_src, (bf16x4*)ksb, 2097152);
  f32_to_bf16<<<8192, 256, 0, stream>>>((const float4*)v_src, (bf16x4*)vsb, 2097152);
  make_wvt<<<dim3(16, 2, 32), 256, 0, stream>>>(v_w, wvt);
  make_wot<<<dim3(16, 2, 32), 256, 0, stream>>>(o_w, wot);
  gating<<<dim3(128, 2), 256, 0, stream>>>(q_src, k_src, sel_v_w, sel_o_w,
                                           bias_v, bias_o, gate_v, gate_o, out);

  const float ssq = 0.29730177875068026f;            // 128^-0.25 (applied to both q and k)
  const float log2e = 1.4426950408889634f;
  gemm_moe<0><<<256, 512, 0, stream>>>(qsb, wqb, nullptr, qb, nullptr, ssq * log2e);
  gemm_moe<0><<<256, 512, 0, stream>>>(ksb, wkb, nullptr, kb, nullptr, ssq);
  gemm_moe<1><<<256, 512, 0, stream>>>(vsb, wvt, gate_v, vbT, nullptr, 1.0f);
  attn_kernel<<<dim3(16, 32), 128, 0, stream>>>(qb, kb, vbT, outb);
  expand_o<<<16384, 256, 0, stream>>>(outb, gate_o, Ae);
  gemm_moe<2><<<256, 512, 0, stream>>>(Ae, wot, nullptr, nullptr, out, 1.0f);
}

// Round 8
// 570.612 us; speedup vs baseline: 1.0756x; 1.0756x over previous
//
#include <hip/hip_runtime.h>
#include <cstdint>
#include <cstddef>

typedef __bf16 bf16;
typedef __bf16 bf16x4 __attribute__((ext_vector_type(4)));
typedef __bf16 bf16x8 __attribute__((ext_vector_type(8)));
typedef float  fx4    __attribute__((ext_vector_type(4)));

// Problem dims (fixed): B=4, S=2048, D=1024, H=8, E=4, DH=128, K_route=2

// async global->LDS DMA, 16 B per lane; dest = wave-uniform base + lane*16 (m97/m104)
__device__ __forceinline__ void async16(const void* g, void* l) {
  __builtin_amdgcn_global_load_lds((const __attribute__((address_space(1))) void*)g,
                                   (__attribute__((address_space(3))) void*)l, 16, 0, 0);
}

#define BARRIER() do { asm volatile("" ::: "memory"); __builtin_amdgcn_s_barrier(); \
                       asm volatile("" ::: "memory"); } while (0)

// DPP row-rotate (within 16-lane rows) — VALU-pipe cross-lane reduce (vs ds_bpermute).
template <int CTRL>
__device__ __forceinline__ float dppf(float x) {
  return __int_as_float(__builtin_amdgcn_update_dpp(
      0, __float_as_int(x), CTRL, 0xf, 0xf, true));
}

// ---------------- fused f32 -> bf16 for all 5 tensors (1 launch, G13-vectorized) -------
__global__ __launch_bounds__(256) void cvt_all(const float4* __restrict__ q,
                                               const float4* __restrict__ k,
                                               const float4* __restrict__ v,
                                               const float4* __restrict__ wq,
                                               const float4* __restrict__ wk,
                                               bf16x4* __restrict__ qo, bf16x4* __restrict__ ko,
                                               bf16x4* __restrict__ vo, bf16x4* __restrict__ wqo,
                                               bf16x4* __restrict__ wko) {
  const int y = blockIdx.y;
  const float4* s; bf16x4* d; int n4;
  if      (y == 0) { s = q;  d = qo;  n4 = 2097152; }
  else if (y == 1) { s = k;  d = ko;  n4 = 2097152; }
  else if (y == 2) { s = v;  d = vo;  n4 = 2097152; }
  else if (y == 3) { s = wq; d = wqo; n4 = 262144; }
  else             { s = wk; d = wko; n4 = 262144; }
  int i = blockIdx.x * 256 + threadIdx.x;
  if (i < n4) {
    float4 t = s[i];
    bf16x4 o;
    o[0] = (bf16)t.x; o[1] = (bf16)t.y; o[2] = (bf16)t.z; o[3] = (bf16)t.w;
    d[i] = o;
  }
}

// fused weight transposes (1 launch): z<32 -> wvt, z>=32 -> wot
// wvt[h][dh][e][k] <- v_w[h][e][k][dh];  wot[d][h][e][dh] <- o_w[h][e][dh][d]
__global__ __launch_bounds__(256) void make_w(const float* __restrict__ v_w,
                                              const float* __restrict__ o_w,
                                              bf16* __restrict__ wvt,
                                              bf16* __restrict__ wot) {
  __shared__ float tile[64][65];
  if (blockIdx.z < 32) {
    const int he = blockIdx.z, k0 = blockIdx.x * 64, dh0 = blockIdx.y * 64;
    const float* in = v_w + (size_t)he * 1024 * 128;
    #pragma unroll
    for (int j = 0; j < 16; j++) {
      int idx = threadIdx.x + j * 256;
      int r = idx >> 6, c = idx & 63;                 // r=k, c=dh
      tile[r][c] = in[(size_t)(k0 + r) * 128 + dh0 + c];
    }
    __syncthreads();
    const int h = he >> 2, e = he & 3;
    bf16* outp = wvt + ((size_t)(h * 128 + dh0) * 4 + e) * 1024 + k0;
    #pragma unroll
    for (int j = 0; j < 16; j++) {
      int idx = threadIdx.x + j * 256;
      int r = idx >> 6, c = idx & 63;                 // r=dh, c=k
      outp[(size_t)r * 4096 + c] = (bf16)tile[c][r];
    }
  } else {
    const int he = blockIdx.z - 32, d0 = blockIdx.x * 64, dh0 = blockIdx.y * 64;
    const float* in = o_w + (size_t)he * 128 * 1024;
    #pragma unroll
    for (int j = 0; j < 16; j++) {
      int idx = threadIdx.x + j * 256;
      int r = idx >> 6, c = idx & 63;                 // r=dh, c=d
      tile[r][c] = in[(size_t)(dh0 + r) * 1024 + d0 + c];
    }
    __syncthreads();
    bf16* outp = wot + (size_t)d0 * 4096 + he * 128 + dh0;
    #pragma unroll
    for (int j = 0; j < 16; j++) {
      int idx = threadIdx.x + j * 256;
      int r = idx >> 6, c = idx & 63;                 // r=d, c=dh
      outp[(size_t)r * 4096 + c] = (bf16)tile[c][r];
    }
  }
}

// ---------------- gating (R6): register-blocked LDS-staged mini-GEMM ----------------
__global__ __launch_bounds__(256) void gating(const float* __restrict__ q_src,
                                              const float* __restrict__ k_src,
                                              const float* __restrict__ sel_v_w,
                                              const float* __restrict__ sel_o_w,
                                              const float* __restrict__ bias_v,
                                              const float* __restrict__ bias_o,
                                              float* __restrict__ gate_v,
                                              float* __restrict__ gate_o,
                                              float* __restrict__ d_out) {
  const int g = blockIdx.y;
  const int m0 = blockIdx.x * 64;
  const float* x = g ? q_src : k_src;
  const float* w = g ? sel_o_w : sel_v_w;
  const float* bias = g ? bias_o : bias_v;
  float* gate = g ? gate_o : gate_v;
  float* idxo = d_out + 8388608 + g * 131072;       // v_idx then o_idx, as float values

  // [buf][ xs 64x128 f32 | ws 32x128 f32 ] = 2 x 48 KB
  __shared__ __align__(16) float smem[2 * 12288];

  const int t = threadIdx.x;
  const int hg = t & 7;          // head
  const int tg = t >> 3;         // token pair 0..31

  auto stage = [&](int buf, int k0) {
    float* xs = smem + buf * 12288;
    float* ws = xs + 8192;
    #pragma unroll
    for (int p = 0; p < 8; p++) {                    // xs: 64 rows x 128 f32
      int of = p * 1024 + t * 4;
      int row = of >> 7, c = (of >> 2) & 31;
      int sc = c ^ ((row >> 1) & 7);                 // pre-swizzled source chunk
      async16(x + (size_t)(m0 + row) * 1024 + k0 + sc * 4, xs + of);
    }
    #pragma unroll
    for (int p = 0; p < 4; p++) {                    // ws: 32 rows x 128 f32
      int of = p * 1024 + t * 4;
      int row = of >> 7, c = (of >> 2) & 31;
      int sc = c ^ ((row >> 2) & 7);
      async16(w + (size_t)row * 1024 + k0 + sc * 4, ws + of);
    }
  };

  double acc[2][4] = {};

  stage(0, 0);
  int buf = 0;
  for (int c8 = 0; c8 < 8; c8++) {
    if (c8 < 7) {
      stage(buf ^ 1, (c8 + 1) * 128);                  // prefetch next chunk
      asm volatile("s_waitcnt vmcnt(12)" ::: "memory"); // wait current chunk only
    } else {
      asm volatile("s_waitcnt vmcnt(0)" ::: "memory");
    }
    BARRIER();
    const float* xs = smem + buf * 12288;
    const float* ws = xs + 8192;
    const int xr0 = tg * 2;
    #pragma unroll 4
    for (int k4 = 0; k4 < 32; k4++) {
      float4 x0 = *(const float4*)(xs + (size_t)xr0 * 128 + (size_t)((k4 ^ (tg & 7)) * 4));
      float4 x1 = *(const float4*)(xs + (size_t)(xr0 + 1) * 128 + (size_t)((k4 ^ (tg & 7)) * 4));
      double x0d[4] = {(double)x0.x, (double)x0.y, (double)x0.z, (double)x0.w};
      double x1d[4] = {(double)x1.x, (double)x1.y, (double)x1.z, (double)x1.w};
      #pragma unroll
      for (int e = 0; e < 4; e++) {
        int wr = hg * 4 + e;
        float4 wv = *(const float4*)(ws + (size_t)wr * 128 + (size_t)((k4 ^ hg) * 4));
        double w0 = (double)wv.x, w1 = (double)wv.y, w2 = (double)wv.z, w3 = (double)wv.w;
        acc[0][e] += x0d[0] * w0 + x0d[1] * w1 + x0d[2] * w2 + x0d[3] * w3;
        acc[1][e] += x1d[0] * w0 + x1d[1] * w1 + x1d[2] * w2 + x1d[3] * w3;
      }
    }
    BARRIER();   // all waves done with buf before it is re-staged next iteration
    buf ^= 1;
  }

  const float log2e = 1.4426950408889634f;
  float b0 = bias[0], b1 = bias[1], b2 = bias[2], b3 = bias[3];
  #pragma unroll
  for (int tok = 0; tok < 2; tok++) {
    int m = m0 + tg * 2 + tok;
    float sel[4];
    #pragma unroll
    for (int e = 0; e < 4; e++) {
      float lv = (float)acc[tok][e];
      sel[e] = 1.0f / (1.0f + __builtin_amdgcn_exp2f(-lv * log2e));
    }
    float vb[4] = {sel[0] + b0, sel[1] + b1, sel[2] + b2, sel[3] + b3};
    int i0 = 0;
    #pragma unroll
    for (int e = 1; e < 4; e++) if (vb[e] > vb[i0]) i0 = e;
    int i1 = -1; float best = -1e30f;
    #pragma unroll
    for (int e = 0; e < 4; e++) { if (e == i0) continue; if (vb[e] > best) { best = vb[e]; i1 = e; } }
    float4 gv;
    gv.x = (i0 == 0 || i1 == 0) ? sel[0] : 0.f;
    gv.y = (i0 == 1 || i1 == 1) ? sel[1] : 0.f;
    gv.z = (i0 == 2 || i1 == 2) ? sel[2] : 0.f;
    gv.w = (i0 == 3 || i1 == 3) ? sel[3] : 0.f;
    *(float4*)(gate + ((size_t)m * 8 + hg) * 4) = gv;
    idxo[m * 16 + hg * 2 + 0] = (float)i0;
    idxo[m * 16 + hg * 2 + 1] = (float)i1;
  }
}

// ---------------- GEMM: C[M x N] = A @ BT^T, bf16 MFMA 16x16x32 ----------------
// R5 structure: 256x128 tile, 8 waves, BK=64, dbuf 96 KB LDS, counted vmcnt(6), phase-split
// MFMA with setprio, T2 swizzle, T1 XCD panels. R8: MODE 0 fuses the Q and K GEMMs into
// one 512-block launch (bid>>8 selects the set) — backfill removes the inter-launch drain.
template <int MODE>
__global__ __launch_bounds__(512) void gemm_moe(const bf16* __restrict__ Abf,
                                                const bf16* __restrict__ BT,
                                                const float* __restrict__ gate,
                                                bf16* __restrict__ Cbf,
                                                float* __restrict__ Cf32,
                                                float scale,
                                                const bf16* __restrict__ Abf2,
                                                const bf16* __restrict__ BT2,
                                                bf16* __restrict__ Cbf2,
                                                float scale2) {
  constexpr int KDIM = (MODE == 0) ? 1024 : 4096;
  constexpr int ASTRIDE = (MODE == 2) ? 4096 : 1024;
  __shared__ __align__(16) bf16 smem[49152];   // [2][A 256x64] + [2][B 128x64] = 96 KB
  const int t = threadIdx.x;
  const int wave = t >> 6, lane = t & 63;
  const int wr = wave >> 1, wc = wave & 1;          // 4 M-groups x 2 N-groups
  const int quad = lane >> 4, l16 = lane & 15;
  const int bid = blockIdx.x;
  const int sel = (MODE == 0) ? (bid >> 8) : 0;
  const bf16* A  = sel ? Abf2 : Abf;
  const bf16* Bt = sel ? BT2  : BT;
  bf16* Cb       = sel ? Cbf2 : Cbf;
  const float scl = sel ? scale2 : scale;
  const int lbid = (MODE == 0) ? (bid & 255) : bid;
  const int m0 = (lbid >> 3) * 256;
  const int n0 = (MODE == 1) ? 0 : (lbid & 7) * 128;
  const int h = (MODE == 1) ? (lbid & 7) : 0;
  const bf16* BTh = (MODE == 1) ? Bt + (size_t)h * 128 * 4096 : Bt;

  fx4 acc[4][4] = {};    // per-wave 64x64 output (4 mi x 4 ni)
  fx4 accT[4][4] = {};   // gated total (mode 1 only; DCE'd otherwise)

  const int srow = t >> 3, sch = t & 7;   // staging: 64 rows x 8 chunks (16 B) per pass

  auto stage = [&](int buf, int k0) {
    bf16* As = smem + buf * 16384;
    bf16* Bs = smem + 32768 + buf * 8192;
    #pragma unroll
    for (int p = 0; p < 2; p++) {                    // B: 128 rows
      int row = p * 64 + srow;
      int sc = sch ^ (row & 7);
      async16(BTh + (size_t)(n0 + row) * KDIM + k0 + sc * 8,
              Bs + row * 64 + sch * 8);
    }
    int col = (MODE == 1) ? (k0 & 1023) : k0;
    #pragma unroll
    for (int p = 0; p < 4; p++) {                    // A: 256 rows
      int row = p * 64 + srow;
      int sc = sch ^ (row & 7);
      async16(A + (size_t)(m0 + row) * ASTRIDE + col + sc * 8,
              As + row * 64 + sch * 8);
    }
  };

  stage(0, 0);
  int buf = 0;
  for (int k0 = 0; k0 < KDIM; k0 += 64) {
    if (k0 + 64 < KDIM) {
      stage(buf ^ 1, k0 + 64);                         // prefetch next K-tile
      asm volatile("s_waitcnt vmcnt(6)" ::: "memory"); // wait current tile only
    } else {
      asm volatile("s_waitcnt vmcnt(0)" ::: "memory");
    }
    BARRIER();
    const bf16* As = smem + buf * 16384;
    const bf16* Bs = smem + 32768 + buf * 8192;
    #pragma unroll
    for (int kk = 0; kk < 64; kk += 32) {
      bf16x8 af[4], bfr[4];
      // phase A: A-frags + B-frags ni 0,1
      #pragma unroll
      for (int i = 0; i < 4; i++) {
        int ar = wr * 64 + i * 16 + l16;
        af[i] = *(const bf16x8*)(As + ar * 64 + ((((kk >> 3) + quad) ^ (ar & 7)) * 8));
      }
      #pragma unroll
      for (int i = 0; i < 2; i++) {
        int br = wc * 64 + i * 16 + l16;
        bfr[i] = *(const bf16x8*)(Bs + br * 64 + ((((kk >> 3) + quad) ^ (br & 7)) * 8));
      }
      BARRIER();
      __builtin_amdgcn_s_setprio(1);
      #pragma unroll
      for (int mi = 0; mi < 4; mi++)
        #pragma unroll
        for (int ni = 0; ni < 2; ni++)
          acc[mi][ni] = __builtin_amdgcn_mfma_f32_16x16x32_bf16(af[mi], bfr[ni], acc[mi][ni], 0, 0, 0);
      __builtin_amdgcn_s_setprio(0);
      BARRIER();
      // phase B: B-frags ni 2,3 (af held in regs)
      #pragma unroll
      for (int i = 2; i < 4; i++) {
        int br = wc * 64 + i * 16 + l16;
        bfr[i] = *(const bf16x8*)(Bs + br * 64 + ((((kk >> 3) + quad) ^ (br & 7)) * 8));
      }
      BARRIER();
      __builtin_amdgcn_s_setprio(1);
      #pragma unroll
      for (int mi = 0; mi < 4; mi++)
        #pragma unroll
        for (int ni = 2; ni < 4; ni++)
          acc[mi][ni] = __builtin_amdgcn_mfma_f32_16x16x32_bf16(af[mi], bfr[ni], acc[mi][ni], 0, 0, 0);
      __builtin_amdgcn_s_setprio(0);
      BARRIER();
    }
    if constexpr (MODE == 1) {
      if (((k0 + 64) & 1023) == 0) {     // expert-chunk boundary: 4 merges total
        const int e = k0 >> 10;
        #pragma unroll
        for (int mi = 0; mi < 4; mi++)
          #pragma unroll
          for (int r = 0; r < 4; r++) {
            int m = m0 + wr * 64 + mi * 16 + quad * 4 + r;
            float gv = gate[((size_t)m * 8 + h) * 4 + e];
            #pragma unroll
            for (int ni = 0; ni < 4; ni++)
              accT[mi][ni][r] += gv * acc[mi][ni][r];
          }
        #pragma unroll
        for (int mi = 0; mi < 4; mi++)
          #pragma unroll
          for (int ni = 0; ni < 4; ni++)
            #pragma unroll
            for (int j = 0; j < 4; j++) acc[mi][ni][j] = 0.f;
      }
    }
    buf ^= 1;
  }

  if (MODE == 1) {
    // transpose through LDS -> vbT[b,h,dh,s] with coalesced global writes
    #pragma unroll
    for (int mi = 0; mi < 4; mi++)
      #pragma unroll
      for (int ni = 0; ni < 4; ni++) {
        int nl = wc * 64 + ni * 16 + l16;
        int ml = wr * 64 + mi * 16 + quad * 4;
        bf16x4 pk;
        #pragma unroll
        for (int r = 0; r < 4; r++) pk[r] = (bf16)accT[mi][ni][r];
        *(bf16x4*)(smem + nl * 264 + ml) = pk;
      }
    __syncthreads();
    int b = m0 >> 11, s0 = m0 & 2047;
    const int row = t >> 2, seg = t & 3;
    bf16* dst = Cb + (((size_t)(b * 8 + h) * 128) + row) * 2048 + s0 + seg * 64;
    #pragma unroll
    for (int j = 0; j < 8; j++)
      *(float4*)(dst + j * 8) = *(float4*)(smem + row * 264 + seg * 64 + j * 8);
    return;
  }

  // epilogue: C/D layout col=lane&15, row=quad*4+reg
  #pragma unroll
  for (int mi = 0; mi < 4; mi++)
    #pragma unroll
    for (int ni = 0; ni < 4; ni++)
      #pragma unroll
      for (int r = 0; r < 4; r++) {
        int m = m0 + wr * 64 + mi * 16 + quad * 4 + r;
        int n = n0 + wc * 64 + ni * 16 + l16;
        float v = acc[mi][ni][r] * scl;
        if (MODE == 0) {
          int b = m >> 11, s = m & 2047, hh = n >> 7, dh = n & 127;
          Cb[(((size_t)(b * 8 + hh) * 2048 + s) << 7) + dh] = (bf16)v;
        } else {
          Cf32[(size_t)m * 1024 + n] = v;
        }
      }
}

// ---------------- flash attention (causal) ----------------
// R8 = R6 4-wave structure (104.8 us known-good; 2 waves/SIMD TLP) + R7's XCD-cluster
// remap (proven FETCH 194->29 MB) + T13 defer-max (skip m/alpha/acc_o-rescale when
// __all(mx <= m_run+8): wave-uniform branch, P bounded by 2^8 which f32/bf16 tolerate)
// + fused expand_o epilogue: writes Ae[token][(h*4+e)*128+dh] = o * gate_o directly
// (deletes the 15 us expand_o kernel and one bf16 rounding).
__global__ __launch_bounds__(256) void attn_kernel(const bf16* __restrict__ qb,
                                                   const bf16* __restrict__ kb,
                                                   const bf16* __restrict__ vbT,
                                                   const float* __restrict__ gate_o,
                                                   bf16* __restrict__ Ae) {
  // XCD-clustering remap: all 16 pair-blocks of one bh land on one XCD (XCD = linear%8).
  const int linear = blockIdx.y * 16 + blockIdx.x;
  const int bh = (linear & 7) * 4 + ((linear >> 3) & 3);
  const int px = linear >> 5;                      // pair index 0..15
  const int b = bh >> 3, h = bh & 7;
  __shared__ __align__(16) bf16 Ks[2][64 * 128];    // [buf][k-row * 128 + dh], swizzled
  __shared__ __align__(16) bf16 VTs[2][128 * 64];   // [buf][dh-row * 64 + s], swizzled
  __shared__ __align__(16) bf16 Ps[4][16][72];
  const int t = threadIdx.x, wave = t >> 6, lane = t & 63;
  const int quad = lane >> 4, l16 = lane & 15;
  const bf16* qbase  = qb  + (size_t)bh * 2048 * 128;
  const bf16* kbase  = kb  + (size_t)bh * 2048 * 128;
  const bf16* vtbase = vbT + (size_t)bh * 128 * 2048;

  auto stage = [&](int buf, int kt) {
    #pragma unroll
    for (int p = 0; p < 4; p++) {
      int o = p * 4096 + wave * 1024 + lane * 16;        // byte offset in 16 KiB tile
      int kr = o >> 8, kc = o & 255;                     // 256 B rows (128 bf16)
      async16((const char*)kbase + (size_t)(kt * 64 + kr) * 256 + (kc ^ ((kr & 7) << 4)),
              (char*)&Ks[buf][0] + o);
    }
    #pragma unroll
    for (int p = 0; p < 4; p++) {
      int o = p * 4096 + wave * 1024 + lane * 16;
      int vr = o >> 7, vc = o & 127;                     // 128 B rows (64 bf16)
      async16((const char*)vtbase + (size_t)vr * 4096 + kt * 128 + (vc ^ ((vr & 7) << 4)),
              (char*)&VTs[buf][0] + o);
    }
  };

  #pragma unroll 1
  for (int pass = 0; pass < 2; pass++) {
    const int qt = pass ? px : (31 - px);                // heavy tile first

    bf16x8 qf[4];
    #pragma unroll
    for (int dk = 0; dk < 4; dk++)
      qf[dk] = *(const bf16x8*)(qbase + (size_t)(qt * 64 + wave * 16 + l16) * 128 + dk * 32 + quad * 8);

    float m_run[4], l_run[4];
    fx4 acc_o[8] = {};
    #pragma unroll
    for (int r = 0; r < 4; r++) { m_run[r] = -1e30f; l_run[r] = 0.f; }

    stage(0, 0);
    int cur = 0;

    for (int kt = 0; kt <= qt; kt++) {
      if (kt < qt) {
        stage(cur ^ 1, kt + 1);                            // prefetch next tile
        asm volatile("s_waitcnt vmcnt(8)" ::: "memory");   // wait tile kt only
      } else {
        asm volatile("s_waitcnt vmcnt(0)" ::: "memory");
      }
      __builtin_amdgcn_s_barrier();
      asm volatile("" ::: "memory");

      const char* Ksb  = (const char*)&Ks[cur][0];
      const char* VTsb = (const char*)&VTs[cur][0];

      fx4 accs[4] = {};
      __builtin_amdgcn_s_setprio(1);
      #pragma unroll
      for (int ni = 0; ni < 4; ni++)
        #pragma unroll
        for (int dk = 0; dk < 4; dk++) {
          int r = ni * 16 + l16;
          bf16x8 kf = *(const bf16x8*)(Ksb + r * 256 + ((dk * 64 + quad * 16) ^ ((r & 7) << 4)));
          accs[ni] = __builtin_amdgcn_mfma_f32_16x16x32_bf16(qf[dk], kf, accs[ni], 0, 0, 0);
        }
      __builtin_amdgcn_s_setprio(0);

      if (kt == qt) {   // causal mask on the diagonal tile
        #pragma unroll
        for (int ni = 0; ni < 4; ni++)
          #pragma unroll
          for (int r = 0; r < 4; r++) {
            int qr = wave * 16 + quad * 4 + r;
            int kc = ni * 16 + l16;
            if (kc > qr) accs[ni][r] = -1e30f;
          }
      }

      // softmax in exp2 domain; DPP row_ror reductions; T13 defer-max
      float mxv[4];
      #pragma unroll
      for (int r = 0; r < 4; r++) {
        float mx = fmaxf(fmaxf(accs[0][r], accs[1][r]), fmaxf(accs[2][r], accs[3][r]));
        mx = fmaxf(mx, dppf<0x121>(mx));
        mx = fmaxf(mx, dppf<0x122>(mx));
        mx = fmaxf(mx, dppf<0x124>(mx));
        mx = fmaxf(mx, dppf<0x128>(mx));
        mxv[r] = mx;
      }
      bool defer = (mxv[0] <= m_run[0] + 8.f) && (mxv[1] <= m_run[1] + 8.f) &&
                   (mxv[2] <= m_run[2] + 8.f) && (mxv[3] <= m_run[3] + 8.f);
      if (__all(defer)) {
        // keep old max: P bounded by 2^8, no acc_o rescale, no alpha
        #pragma unroll
        for (int r = 0; r < 4; r++) {
          float rs = 0.f;
          #pragma unroll
          for (int ni = 0; ni < 4; ni++) {
            float p = __builtin_amdgcn_exp2f(accs[ni][r] - m_run[r]);
            accs[ni][r] = p; rs += p;
          }
          rs += dppf<0x121>(rs);
          rs += dppf<0x122>(rs);
          rs += dppf<0x124>(rs);
          rs += dppf<0x128>(rs);
          l_run[r] += rs;
        }
      } else {
        #pragma unroll
        for (int r = 0; r < 4; r++) {
          float m_new = fmaxf(m_run[r], mxv[r]);
          float alpha = __builtin_amdgcn_exp2f(m_run[r] - m_new);
          float rs = 0.f;
          #pragma unroll
          for (int ni = 0; ni < 4; ni++) {
            float p = __builtin_amdgcn_exp2f(accs[ni][r] - m_new);
            accs[ni][r] = p; rs += p;
          }
          rs += dppf<0x121>(rs);
          rs += dppf<0x122>(rs);
          rs += dppf<0x124>(rs);
          rs += dppf<0x128>(rs);
          l_run[r] = l_run[r] * alpha + rs;
          m_run[r] = m_new;
          #pragma unroll
          for (int nj = 0; nj < 8; nj++) acc_o[nj][r] *= alpha;
        }
      }

      // P: C-layout -> LDS -> A-layout (per-wave region; DS in-order within a wave)
      #pragma unroll
      for (int ni = 0; ni < 4; ni++)
        #pragma unroll
        for (int r = 0; r < 4; r++)
          Ps[wave][quad * 4 + r][ni * 16 + l16] = (bf16)accs[ni][r];

      __builtin_amdgcn_s_setprio(1);
      #pragma unroll
      for (int step = 0; step < 2; step++) {
        bf16x8 pf = *(const bf16x8*)&Ps[wave][l16][step * 32 + quad * 8];
        #pragma unroll
        for (int nj = 0; nj < 8; nj++) {
          int r = nj * 16 + l16;
          bf16x8 vf = *(const bf16x8*)(VTsb + r * 128 + ((step * 64 + quad * 16) ^ ((r & 7) << 4)));
          acc_o[nj] = __builtin_amdgcn_mfma_f32_16x16x32_bf16(pf, vf, acc_o[nj], 0, 0, 0);
        }
      }
      __builtin_amdgcn_s_setprio(0);

      asm volatile("" ::: "memory");
      __builtin_amdgcn_s_barrier();   // all waves done reading buf[cur] before re-stage
      cur ^= 1;
    }

    // fused expand_o epilogue: Ae[token][(h*4+e)*128 + dh] = (o / l) * gate_o[token][h][e]
    #pragma unroll
    for (int r = 0; r < 4; r++) {
      int s = qt * 64 + wave * 16 + quad * 4 + r;
      int token = b * 2048 + s;
      float4 g4 = *(const float4*)(gate_o + ((size_t)token * 8 + h) * 4);
      float inv = 1.0f / l_run[r];
      #pragma unroll
      for (int nj = 0; nj < 8; nj++) {
        float o = acc_o[nj][r] * inv;
        bf16* dst = Ae + (size_t)token * 4096 + (h * 4) * 128 + nj * 16 + l16;
        dst[0]   = (bf16)(o * g4.x);
        dst[128] = (bf16)(o * g4.y);
        dst[256] = (bf16)(o * g4.z);
        dst[384] = (bf16)(o * g4.w);
      }
    }
  }
}

// ---------------- launch ----------------
extern "C" void kernel_launch(void* const* d_in, const int* in_sizes, int n_in,
                              void* d_out, int out_size, void* d_ws, size_t ws_size,
                              hipStream_t stream) {
  const float* q_src  = (const float*)d_in[0];
  const float* k_src  = (const float*)d_in[1];
  const float* v_src  = (const float*)d_in[2];
  const float* wq     = (const float*)d_in[3];
  const float* wk     = (const float*)d_in[4];
  const float* sel_v_w = (const float*)d_in[5];
  const float* sel_o_w = (const float*)d_in[6];
  const float* v_w    = (const float*)d_in[7];
  const float* o_w    = (const float*)d_in[8];
  const float* bias_v = (const float*)d_in[9];
  const float* bias_o = (const float*)d_in[10];
  float* out = (float*)d_out;

  char* ws = (char*)d_ws;
  size_t off = 0;
  auto alloc = [&](size_t bytes) { char* p = ws + off; off += (bytes + 255) & ~(size_t)255; return p; };
  bf16* wqb   = (bf16*)alloc((size_t)1024 * 1024 * 2);
  bf16* wkb   = (bf16*)alloc((size_t)1024 * 1024 * 2);
  bf16* wvt   = (bf16*)alloc((size_t)8 * 128 * 4 * 1024 * 2);
  bf16* wot   = (bf16*)alloc((size_t)1024 * 4096 * 2);
  float* gate_v = (float*)alloc((size_t)8192 * 32 * 4);
  float* gate_o = (float*)alloc((size_t)8192 * 32 * 4);
  // Ae (8192 x 4096 bf16 = 64 MB) overlays qsb+ksb+vsb+pad — all dead when attn runs
  // (qsb/ksb consumed by fused gemm0, vsb by gemm1; qb/kb/vbT live AFTER this span).
  bf16* qsb   = (bf16*)alloc((size_t)8192 * 1024 * 2);   // bf16 copies of srcs
  bf16* ksb   = (bf16*)alloc((size_t)8192 * 1024 * 2);
  bf16* vsb   = (bf16*)alloc((size_t)8192 * 1024 * 2);
  (void)alloc((size_t)8192 * 1024 * 2);                  // pad to complete Ae's 64 MB
  bf16* Ae    = qsb;
  bf16* qb    = (bf16*)alloc((size_t)8192 * 1024 * 2);   // [b,h,s,dh]
  bf16* kb    = (bf16*)alloc((size_t)8192 * 1024 * 2);   // [b,h,s,dh]
  bf16* vbT   = (bf16*)alloc((size_t)8192 * 1024 * 2);   // [b,h,dh,s]

  cvt_all<<<dim3(8192, 5), 256, 0, stream>>>((const float4*)q_src, (const float4*)k_src,
                                             (const float4*)v_src, (const float4*)wq,
                                             (const float4*)wk, (bf16x4*)qsb, (bf16x4*)ksb,
                                             (bf16x4*)vsb, (bf16x4*)wqb, (bf16x4*)wkb);
  make_w<<<dim3(16, 2, 64), 256, 0, stream>>>(v_w, o_w, wvt, wot);
  gating<<<dim3(128, 2), 256, 0, stream>>>(q_src, k_src, sel_v_w, sel_o_w,
                                           bias_v, bias_o, gate_v, gate_o, out);

  const float ssq = 0.29730177875068026f;            // 128^-0.25 (applied to both q and k)
  const float log2e = 1.4426950408889634f;
  // fused Q/K projection: blocks 0-255 -> Q (scale incl. log2e), 256-511 -> K
  gemm_moe<0><<<512, 512, 0, stream>>>(qsb, wqb, nullptr, qb, nullptr, ssq * log2e,
                                       ksb, wkb, kb, ssq);
  gemm_moe<1><<<256, 512, 0, stream>>>(vsb, wvt, gate_v, vbT, nullptr, 1.0f,
                                       nullptr, nullptr, nullptr, 0.f);
  attn_kernel<<<dim3(16, 32), 256, 0, stream>>>(qb, kb, vbT, gate_o, Ae);
  gemm_moe<2><<<256, 512, 0, stream>>>(Ae, wot, nullptr, nullptr, out, 1.0f,
                                       nullptr, nullptr, nullptr, 0.f);
}

// Round 9
// 566.433 us; speedup vs baseline: 1.0836x; 1.0074x over previous
//
#include <hip/hip_runtime.h>
#include <cstdint>
#include <cstddef>

typedef __bf16 bf16;
typedef __bf16 bf16x4 __attribute__((ext_vector_type(4)));
typedef __bf16 bf16x8 __attribute__((ext_vector_type(8)));
typedef float  fx4    __attribute__((ext_vector_type(4)));

// Problem dims (fixed): B=4, S=2048, D=1024, H=8, E=4, DH=128, K_route=2

// async global->LDS DMA, 16 B per lane; dest = wave-uniform base + lane*16 (m97/m104)
__device__ __forceinline__ void async16(const void* g, void* l) {
  __builtin_amdgcn_global_load_lds((const __attribute__((address_space(1))) void*)g,
                                   (__attribute__((address_space(3))) void*)l, 16, 0, 0);
}

#define BARRIER() do { asm volatile("" ::: "memory"); __builtin_amdgcn_s_barrier(); \
                       asm volatile("" ::: "memory"); } while (0)

// DPP row-rotate (within 16-lane rows) — VALU-pipe cross-lane reduce (vs ds_bpermute).
template <int CTRL>
__device__ __forceinline__ float dppf(float x) {
  return __int_as_float(__builtin_amdgcn_update_dpp(
      0, __float_as_int(x), CTRL, 0xf, 0xf, true));
}

// ---------------- fused f32 -> bf16 for all 5 tensors (1 launch, G13-vectorized) -------
__global__ __launch_bounds__(256) void cvt_all(const float4* __restrict__ q,
                                               const float4* __restrict__ k,
                                               const float4* __restrict__ v,
                                               const float4* __restrict__ wq,
                                               const float4* __restrict__ wk,
                                               bf16x4* __restrict__ qo, bf16x4* __restrict__ ko,
                                               bf16x4* __restrict__ vo, bf16x4* __restrict__ wqo,
                                               bf16x4* __restrict__ wko) {
  const int y = blockIdx.y;
  const float4* s; bf16x4* d; int n4;
  if      (y == 0) { s = q;  d = qo;  n4 = 2097152; }
  else if (y == 1) { s = k;  d = ko;  n4 = 2097152; }
  else if (y == 2) { s = v;  d = vo;  n4 = 2097152; }
  else if (y == 3) { s = wq; d = wqo; n4 = 262144; }
  else             { s = wk; d = wko; n4 = 262144; }
  int i = blockIdx.x * 256 + threadIdx.x;
  if (i < n4) {
    float4 t = s[i];
    bf16x4 o;
    o[0] = (bf16)t.x; o[1] = (bf16)t.y; o[2] = (bf16)t.z; o[3] = (bf16)t.w;
    d[i] = o;
  }
}

// fused weight transposes (1 launch): z<32 -> wvt, z>=32 -> wot
// wvt[h][dh][e][k] <- v_w[h][e][k][dh];  wot[d][h][e][dh] <- o_w[h][e][dh][d]
__global__ __launch_bounds__(256) void make_w(const float* __restrict__ v_w,
                                              const float* __restrict__ o_w,
                                              bf16* __restrict__ wvt,
                                              bf16* __restrict__ wot) {
  __shared__ float tile[64][65];
  if (blockIdx.z < 32) {
    const int he = blockIdx.z, k0 = blockIdx.x * 64, dh0 = blockIdx.y * 64;
    const float* in = v_w + (size_t)he * 1024 * 128;
    #pragma unroll
    for (int j = 0; j < 16; j++) {
      int idx = threadIdx.x + j * 256;
      int r = idx >> 6, c = idx & 63;                 // r=k, c=dh
      tile[r][c] = in[(size_t)(k0 + r) * 128 + dh0 + c];
    }
    __syncthreads();
    const int h = he >> 2, e = he & 3;
    bf16* outp = wvt + ((size_t)(h * 128 + dh0) * 4 + e) * 1024 + k0;
    #pragma unroll
    for (int j = 0; j < 16; j++) {
      int idx = threadIdx.x + j * 256;
      int r = idx >> 6, c = idx & 63;                 // r=dh, c=k
      outp[(size_t)r * 4096 + c] = (bf16)tile[c][r];
    }
  } else {
    const int he = blockIdx.z - 32, d0 = blockIdx.x * 64, dh0 = blockIdx.y * 64;
    const float* in = o_w + (size_t)he * 128 * 1024;
    #pragma unroll
    for (int j = 0; j < 16; j++) {
      int idx = threadIdx.x + j * 256;
      int r = idx >> 6, c = idx & 63;                 // r=dh, c=d
      tile[r][c] = in[(size_t)(dh0 + r) * 1024 + d0 + c];
    }
    __syncthreads();
    bf16* outp = wot + (size_t)d0 * 4096 + he * 128 + dh0;
    #pragma unroll
    for (int j = 0; j < 16; j++) {
      int idx = threadIdx.x + j * 256;
      int r = idx >> 6, c = idx & 63;                 // r=d, c=dh
      outp[(size_t)r * 4096 + c] = (bf16)tile[c][r];
    }
  }
}

// ---------------- gating (R6): register-blocked LDS-staged mini-GEMM ----------------
__global__ __launch_bounds__(256) void gating(const float* __restrict__ q_src,
                                              const float* __restrict__ k_src,
                                              const float* __restrict__ sel_v_w,
                                              const float* __restrict__ sel_o_w,
                                              const float* __restrict__ bias_v,
                                              const float* __restrict__ bias_o,
                                              float* __restrict__ gate_v,
                                              float* __restrict__ gate_o,
                                              float* __restrict__ d_out) {
  const int g = blockIdx.y;
  const int m0 = blockIdx.x * 64;
  const float* x = g ? q_src : k_src;
  const float* w = g ? sel_o_w : sel_v_w;
  const float* bias = g ? bias_o : bias_v;
  float* gate = g ? gate_o : gate_v;
  float* idxo = d_out + 8388608 + g * 131072;       // v_idx then o_idx, as float values

  // [buf][ xs 64x128 f32 | ws 32x128 f32 ] = 2 x 48 KB
  __shared__ __align__(16) float smem[2 * 12288];

  const int t = threadIdx.x;
  const int hg = t & 7;          // head
  const int tg = t >> 3;         // token pair 0..31

  auto stage = [&](int buf, int k0) {
    float* xs = smem + buf * 12288;
    float* ws = xs + 8192;
    #pragma unroll
    for (int p = 0; p < 8; p++) {                    // xs: 64 rows x 128 f32
      int of = p * 1024 + t * 4;
      int row = of >> 7, c = (of >> 2) & 31;
      int sc = c ^ ((row >> 1) & 7);                 // pre-swizzled source chunk
      async16(x + (size_t)(m0 + row) * 1024 + k0 + sc * 4, xs + of);
    }
    #pragma unroll
    for (int p = 0; p < 4; p++) {                    // ws: 32 rows x 128 f32
      int of = p * 1024 + t * 4;
      int row = of >> 7, c = (of >> 2) & 31;
      int sc = c ^ ((row >> 2) & 7);
      async16(w + (size_t)row * 1024 + k0 + sc * 4, ws + of);
    }
  };

  double acc[2][4] = {};

  stage(0, 0);
  int buf = 0;
  for (int c8 = 0; c8 < 8; c8++) {
    if (c8 < 7) {
      stage(buf ^ 1, (c8 + 1) * 128);                  // prefetch next chunk
      asm volatile("s_waitcnt vmcnt(12)" ::: "memory"); // wait current chunk only
    } else {
      asm volatile("s_waitcnt vmcnt(0)" ::: "memory");
    }
    BARRIER();
    const float* xs = smem + buf * 12288;
    const float* ws = xs + 8192;
    const int xr0 = tg * 2;
    #pragma unroll 4
    for (int k4 = 0; k4 < 32; k4++) {
      float4 x0 = *(const float4*)(xs + (size_t)xr0 * 128 + (size_t)((k4 ^ (tg & 7)) * 4));
      float4 x1 = *(const float4*)(xs + (size_t)(xr0 + 1) * 128 + (size_t)((k4 ^ (tg & 7)) * 4));
      double x0d[4] = {(double)x0.x, (double)x0.y, (double)x0.z, (double)x0.w};
      double x1d[4] = {(double)x1.x, (double)x1.y, (double)x1.z, (double)x1.w};
      #pragma unroll
      for (int e = 0; e < 4; e++) {
        int wr = hg * 4 + e;
        float4 wv = *(const float4*)(ws + (size_t)wr * 128 + (size_t)((k4 ^ hg) * 4));
        double w0 = (double)wv.x, w1 = (double)wv.y, w2 = (double)wv.z, w3 = (double)wv.w;
        acc[0][e] += x0d[0] * w0 + x0d[1] * w1 + x0d[2] * w2 + x0d[3] * w3;
        acc[1][e] += x1d[0] * w0 + x1d[1] * w1 + x1d[2] * w2 + x1d[3] * w3;
      }
    }
    BARRIER();   // all waves done with buf before it is re-staged next iteration
    buf ^= 1;
  }

  const float log2e = 1.4426950408889634f;
  float b0 = bias[0], b1 = bias[1], b2 = bias[2], b3 = bias[3];
  #pragma unroll
  for (int tok = 0; tok < 2; tok++) {
    int m = m0 + tg * 2 + tok;
    float sel[4];
    #pragma unroll
    for (int e = 0; e < 4; e++) {
      float lv = (float)acc[tok][e];
      sel[e] = 1.0f / (1.0f + __builtin_amdgcn_exp2f(-lv * log2e));
    }
    float vb[4] = {sel[0] + b0, sel[1] + b1, sel[2] + b2, sel[3] + b3};
    int i0 = 0;
    #pragma unroll
    for (int e = 1; e < 4; e++) if (vb[e] > vb[i0]) i0 = e;
    int i1 = -1; float best = -1e30f;
    #pragma unroll
    for (int e = 0; e < 4; e++) { if (e == i0) continue; if (vb[e] > best) { best = vb[e]; i1 = e; } }
    float4 gv;
    gv.x = (i0 == 0 || i1 == 0) ? sel[0] : 0.f;
    gv.y = (i0 == 1 || i1 == 1) ? sel[1] : 0.f;
    gv.z = (i0 == 2 || i1 == 2) ? sel[2] : 0.f;
    gv.w = (i0 == 3 || i1 == 3) ? sel[3] : 0.f;
    *(float4*)(gate + ((size_t)m * 8 + hg) * 4) = gv;
    idxo[m * 16 + hg * 2 + 0] = (float)i0;
    idxo[m * 16 + hg * 2 + 1] = (float)i1;
  }
}

// ---------------- GEMM: C[M x N] = A @ BT^T, bf16 MFMA 16x16x32 ----------------
// R5 structure: 256x128 tile, 8 waves, BK=64, dbuf 96 KB LDS, counted vmcnt(6), phase-split
// MFMA with setprio, T2 swizzle. R8: MODE 0 fuses Q and K GEMMs (bid>>8 selects set).
// R9 (T1 fix): modes 0/2 remap so the M-TILE is XCD-local, not the N-panel. R8 counters:
// FETCH 282 MB vs 36 MB unique — each A-tile was read by 8 blocks on 8 DIFFERENT XCDs
// (lbid&7 = n-panel = XCD). New mapping mt=(lbid&7)|((lbid>>6)<<3), np=(lbid>>3)&7:
// per XCD = 4 m-tiles x 8 n-panels -> A-tile fetched once (2 MB) + full B (2 MB) = 4 MB
// = exactly one L2. MODE 1 keeps lbid&7 = head (B_h panel 1 MB stays L2-local).
template <int MODE>
__global__ __launch_bounds__(512) void gemm_moe(const bf16* __restrict__ Abf,
                                                const bf16* __restrict__ BT,
                                                const float* __restrict__ gate,
                                                bf16* __restrict__ Cbf,
                                                float* __restrict__ Cf32,
                                                float scale,
                                                const bf16* __restrict__ Abf2,
                                                const bf16* __restrict__ BT2,
                                                bf16* __restrict__ Cbf2,
                                                float scale2) {
  constexpr int KDIM = (MODE == 0) ? 1024 : 4096;
  constexpr int ASTRIDE = (MODE == 2) ? 4096 : 1024;
  __shared__ __align__(16) bf16 smem[49152];   // [2][A 256x64] + [2][B 128x64] = 96 KB
  const int t = threadIdx.x;
  const int wave = t >> 6, lane = t & 63;
  const int wr = wave >> 1, wc = wave & 1;          // 4 M-groups x 2 N-groups
  const int quad = lane >> 4, l16 = lane & 15;
  const int bid = blockIdx.x;
  const int sel = (MODE == 0) ? (bid >> 8) : 0;
  const bf16* A  = sel ? Abf2 : Abf;
  const bf16* Bt = sel ? BT2  : BT;
  bf16* Cb       = sel ? Cbf2 : Cbf;
  const float scl = sel ? scale2 : scale;
  const int lbid = (MODE == 0) ? (bid & 255) : bid;
  // R9 remap: XCD (= bid%8) owns the m-tile for modes 0/2; owns the head for mode 1.
  const int mt = (MODE == 1) ? (lbid >> 3) : ((lbid & 7) | ((lbid >> 6) << 3));
  const int np = (MODE == 1) ? (lbid & 7) : ((lbid >> 3) & 7);
  const int m0 = mt * 256;
  const int n0 = (MODE == 1) ? 0 : np * 128;
  const int h = (MODE == 1) ? np : 0;
  const bf16* BTh = (MODE == 1) ? Bt + (size_t)h * 128 * 4096 : Bt;

  fx4 acc[4][4] = {};    // per-wave 64x64 output (4 mi x 4 ni)
  fx4 accT[4][4] = {};   // gated total (mode 1 only; DCE'd otherwise)

  const int srow = t >> 3, sch = t & 7;   // staging: 64 rows x 8 chunks (16 B) per pass

  auto stage = [&](int buf, int k0) {
    bf16* As = smem + buf * 16384;
    bf16* Bs = smem + 32768 + buf * 8192;
    #pragma unroll
    for (int p = 0; p < 2; p++) {                    // B: 128 rows
      int row = p * 64 + srow;
      int sc = sch ^ (row & 7);
      async16(BTh + (size_t)(n0 + row) * KDIM + k0 + sc * 8,
              Bs + row * 64 + sch * 8);
    }
    int col = (MODE == 1) ? (k0 & 1023) : k0;
    #pragma unroll
    for (int p = 0; p < 4; p++) {                    // A: 256 rows
      int row = p * 64 + srow;
      int sc = sch ^ (row & 7);
      async16(A + (size_t)(m0 + row) * ASTRIDE + col + sc * 8,
              As + row * 64 + sch * 8);
    }
  };

  stage(0, 0);
  int buf = 0;
  for (int k0 = 0; k0 < KDIM; k0 += 64) {
    if (k0 + 64 < KDIM) {
      stage(buf ^ 1, k0 + 64);                         // prefetch next K-tile
      asm volatile("s_waitcnt vmcnt(6)" ::: "memory"); // wait current tile only
    } else {
      asm volatile("s_waitcnt vmcnt(0)" ::: "memory");
    }
    BARRIER();
    const bf16* As = smem + buf * 16384;
    const bf16* Bs = smem + 32768 + buf * 8192;
    #pragma unroll
    for (int kk = 0; kk < 64; kk += 32) {
      bf16x8 af[4], bfr[4];
      // phase A: A-frags + B-frags ni 0,1
      #pragma unroll
      for (int i = 0; i < 4; i++) {
        int ar = wr * 64 + i * 16 + l16;
        af[i] = *(const bf16x8*)(As + ar * 64 + ((((kk >> 3) + quad) ^ (ar & 7)) * 8));
      }
      #pragma unroll
      for (int i = 0; i < 2; i++) {
        int br = wc * 64 + i * 16 + l16;
        bfr[i] = *(const bf16x8*)(Bs + br * 64 + ((((kk >> 3) + quad) ^ (br & 7)) * 8));
      }
      BARRIER();
      __builtin_amdgcn_s_setprio(1);
      #pragma unroll
      for (int mi = 0; mi < 4; mi++)
        #pragma unroll
        for (int ni = 0; ni < 2; ni++)
          acc[mi][ni] = __builtin_amdgcn_mfma_f32_16x16x32_bf16(af[mi], bfr[ni], acc[mi][ni], 0, 0, 0);
      __builtin_amdgcn_s_setprio(0);
      BARRIER();
      // phase B: B-frags ni 2,3 (af held in regs)
      #pragma unroll
      for (int i = 2; i < 4; i++) {
        int br = wc * 64 + i * 16 + l16;
        bfr[i] = *(const bf16x8*)(Bs + br * 64 + ((((kk >> 3) + quad) ^ (br & 7)) * 8));
      }
      BARRIER();
      __builtin_amdgcn_s_setprio(1);
      #pragma unroll
      for (int mi = 0; mi < 4; mi++)
        #pragma unroll
        for (int ni = 2; ni < 4; ni++)
          acc[mi][ni] = __builtin_amdgcn_mfma_f32_16x16x32_bf16(af[mi], bfr[ni], acc[mi][ni], 0, 0, 0);
      __builtin_amdgcn_s_setprio(0);
      BARRIER();
    }
    if constexpr (MODE == 1) {
      if (((k0 + 64) & 1023) == 0) {     // expert-chunk boundary: 4 merges total
        const int e = k0 >> 10;
        #pragma unroll
        for (int mi = 0; mi < 4; mi++)
          #pragma unroll
          for (int r = 0; r < 4; r++) {
            int m = m0 + wr * 64 + mi * 16 + quad * 4 + r;
            float gv = gate[((size_t)m * 8 + h) * 4 + e];
            #pragma unroll
            for (int ni = 0; ni < 4; ni++)
              accT[mi][ni][r] += gv * acc[mi][ni][r];
          }
        #pragma unroll
        for (int mi = 0; mi < 4; mi++)
          #pragma unroll
          for (int ni = 0; ni < 4; ni++)
            #pragma unroll
            for (int j = 0; j < 4; j++) acc[mi][ni][j] = 0.f;
      }
    }
    buf ^= 1;
  }

  if (MODE == 1) {
    // transpose through LDS -> vbT[b,h,dh,s] with coalesced global writes
    #pragma unroll
    for (int mi = 0; mi < 4; mi++)
      #pragma unroll
      for (int ni = 0; ni < 4; ni++) {
        int nl = wc * 64 + ni * 16 + l16;
        int ml = wr * 64 + mi * 16 + quad * 4;
        bf16x4 pk;
        #pragma unroll
        for (int r = 0; r < 4; r++) pk[r] = (bf16)accT[mi][ni][r];
        *(bf16x4*)(smem + nl * 264 + ml) = pk;
      }
    __syncthreads();
    int b = m0 >> 11, s0 = m0 & 2047;
    const int row = t >> 2, seg = t & 3;
    bf16* dst = Cb + (((size_t)(b * 8 + h) * 128) + row) * 2048 + s0 + seg * 64;
    #pragma unroll
    for (int j = 0; j < 8; j++)
      *(float4*)(dst + j * 8) = *(float4*)(smem + row * 264 + seg * 64 + j * 8);
    return;
  }

  // epilogue: C/D layout col=lane&15, row=quad*4+reg
  #pragma unroll
  for (int mi = 0; mi < 4; mi++)
    #pragma unroll
    for (int ni = 0; ni < 4; ni++)
      #pragma unroll
      for (int r = 0; r < 4; r++) {
        int m = m0 + wr * 64 + mi * 16 + quad * 4 + r;
        int n = n0 + wc * 64 + ni * 16 + l16;
        float v = acc[mi][ni][r] * scl;
        if (MODE == 0) {
          int b = m >> 11, s = m & 2047, hh = n >> 7, dh = n & 127;
          Cb[(((size_t)(b * 8 + hh) * 2048 + s) << 7) + dh] = (bf16)v;
        } else {
          Cf32[(size_t)m * 1024 + n] = v;
        }
      }
}

// ---------------- flash attention (causal) ----------------
// R8 = R6 4-wave structure + XCD-cluster remap (FETCH 194->29 MB) + T13 defer-max +
// fused expand_o epilogue. Counters R8: dur 94.2, VALU 45.6%, Mfma 15.3%, occ 19.6%.
__global__ __launch_bounds__(256) void attn_kernel(const bf16* __restrict__ qb,
                                                   const bf16* __restrict__ kb,
                                                   const bf16* __restrict__ vbT,
                                                   const float* __restrict__ gate_o,
                                                   bf16* __restrict__ Ae) {
  // XCD-clustering remap: all 16 pair-blocks of one bh land on one XCD (XCD = linear%8).
  const int linear = blockIdx.y * 16 + blockIdx.x;
  const int bh = (linear & 7) * 4 + ((linear >> 3) & 3);
  const int px = linear >> 5;                      // pair index 0..15
  const int b = bh >> 3, h = bh & 7;
  __shared__ __align__(16) bf16 Ks[2][64 * 128];    // [buf][k-row * 128 + dh], swizzled
  __shared__ __align__(16) bf16 VTs[2][128 * 64];   // [buf][dh-row * 64 + s], swizzled
  __shared__ __align__(16) bf16 Ps[4][16][72];
  const int t = threadIdx.x, wave = t >> 6, lane = t & 63;
  const int quad = lane >> 4, l16 = lane & 15;
  const bf16* qbase  = qb  + (size_t)bh * 2048 * 128;
  const bf16* kbase  = kb  + (size_t)bh * 2048 * 128;
  const bf16* vtbase = vbT + (size_t)bh * 128 * 2048;

  auto stage = [&](int buf, int kt) {
    #pragma unroll
    for (int p = 0; p < 4; p++) {
      int o = p * 4096 + wave * 1024 + lane * 16;        // byte offset in 16 KiB tile
      int kr = o >> 8, kc = o & 255;                     // 256 B rows (128 bf16)
      async16((const char*)kbase + (size_t)(kt * 64 + kr) * 256 + (kc ^ ((kr & 7) << 4)),
              (char*)&Ks[buf][0] + o);
    }
    #pragma unroll
    for (int p = 0; p < 4; p++) {
      int o = p * 4096 + wave * 1024 + lane * 16;
      int vr = o >> 7, vc = o & 127;                     // 128 B rows (64 bf16)
      async16((const char*)vtbase + (size_t)vr * 4096 + kt * 128 + (vc ^ ((vr & 7) << 4)),
              (char*)&VTs[buf][0] + o);
    }
  };

  #pragma unroll 1
  for (int pass = 0; pass < 2; pass++) {
    const int qt = pass ? px : (31 - px);                // heavy tile first

    bf16x8 qf[4];
    #pragma unroll
    for (int dk = 0; dk < 4; dk++)
      qf[dk] = *(const bf16x8*)(qbase + (size_t)(qt * 64 + wave * 16 + l16) * 128 + dk * 32 + quad * 8);

    float m_run[4], l_run[4];
    fx4 acc_o[8] = {};
    #pragma unroll
    for (int r = 0; r < 4; r++) { m_run[r] = -1e30f; l_run[r] = 0.f; }

    stage(0, 0);
    int cur = 0;

    for (int kt = 0; kt <= qt; kt++) {
      if (kt < qt) {
        stage(cur ^ 1, kt + 1);                            // prefetch next tile
        asm volatile("s_waitcnt vmcnt(8)" ::: "memory");   // wait tile kt only
      } else {
        asm volatile("s_waitcnt vmcnt(0)" ::: "memory");
      }
      __builtin_amdgcn_s_barrier();
      asm volatile("" ::: "memory");

      const char* Ksb  = (const char*)&Ks[cur][0];
      const char* VTsb = (const char*)&VTs[cur][0];

      fx4 accs[4] = {};
      __builtin_amdgcn_s_setprio(1);
      #pragma unroll
      for (int ni = 0; ni < 4; ni++)
        #pragma unroll
        for (int dk = 0; dk < 4; dk++) {
          int r = ni * 16 + l16;
          bf16x8 kf = *(const bf16x8*)(Ksb + r * 256 + ((dk * 64 + quad * 16) ^ ((r & 7) << 4)));
          accs[ni] = __builtin_amdgcn_mfma_f32_16x16x32_bf16(qf[dk], kf, accs[ni], 0, 0, 0);
        }
      __builtin_amdgcn_s_setprio(0);

      if (kt == qt) {   // causal mask on the diagonal tile
        #pragma unroll
        for (int ni = 0; ni < 4; ni++)
          #pragma unroll
          for (int r = 0; r < 4; r++) {
            int qr = wave * 16 + quad * 4 + r;
            int kc = ni * 16 + l16;
            if (kc > qr) accs[ni][r] = -1e30f;
          }
      }

      // softmax in exp2 domain; DPP row_ror reductions; T13 defer-max
      float mxv[4];
      #pragma unroll
      for (int r = 0; r < 4; r++) {
        float mx = fmaxf(fmaxf(accs[0][r], accs[1][r]), fmaxf(accs[2][r], accs[3][r]));
        mx = fmaxf(mx, dppf<0x121>(mx));
        mx = fmaxf(mx, dppf<0x122>(mx));
        mx = fmaxf(mx, dppf<0x124>(mx));
        mx = fmaxf(mx, dppf<0x128>(mx));
        mxv[r] = mx;
      }
      bool defer = (mxv[0] <= m_run[0] + 8.f) && (mxv[1] <= m_run[1] + 8.f) &&
                   (mxv[2] <= m_run[2] + 8.f) && (mxv[3] <= m_run[3] + 8.f);
      if (__all(defer)) {
        // keep old max: P bounded by 2^8, no acc_o rescale, no alpha
        #pragma unroll
        for (int r = 0; r < 4; r++) {
          float rs = 0.f;
          #pragma unroll
          for (int ni = 0; ni < 4; ni++) {
            float p = __builtin_amdgcn_exp2f(accs[ni][r] - m_run[r]);
            accs[ni][r] = p; rs += p;
          }
          rs += dppf<0x121>(rs);
          rs += dppf<0x122>(rs);
          rs += dppf<0x124>(rs);
          rs += dppf<0x128>(rs);
          l_run[r] += rs;
        }
      } else {
        #pragma unroll
        for (int r = 0; r < 4; r++) {
          float m_new = fmaxf(m_run[r], mxv[r]);
          float alpha = __builtin_amdgcn_exp2f(m_run[r] - m_new);
          float rs = 0.f;
          #pragma unroll
          for (int ni = 0; ni < 4; ni++) {
            float p = __builtin_amdgcn_exp2f(accs[ni][r] - m_new);
            accs[ni][r] = p; rs += p;
          }
          rs += dppf<0x121>(rs);
          rs += dppf<0x122>(rs);
          rs += dppf<0x124>(rs);
          rs += dppf<0x128>(rs);
          l_run[r] = l_run[r] * alpha + rs;
          m_run[r] = m_new;
          #pragma unroll
          for (int nj = 0; nj < 8; nj++) acc_o[nj][r] *= alpha;
        }
      }

      // P: C-layout -> LDS -> A-layout (per-wave region; DS in-order within a wave)
      #pragma unroll
      for (int ni = 0; ni < 4; ni++)
        #pragma unroll
        for (int r = 0; r < 4; r++)
          Ps[wave][quad * 4 + r][ni * 16 + l16] = (bf16)accs[ni][r];

      __builtin_amdgcn_s_setprio(1);
      #pragma unroll
      for (int step = 0; step < 2; step++) {
        bf16x8 pf = *(const bf16x8*)&Ps[wave][l16][step * 32 + quad * 8];
        #pragma unroll
        for (int nj = 0; nj < 8; nj++) {
          int r = nj * 16 + l16;
          bf16x8 vf = *(const bf16x8*)(VTsb + r * 128 + ((step * 64 + quad * 16) ^ ((r & 7) << 4)));
          acc_o[nj] = __builtin_amdgcn_mfma_f32_16x16x32_bf16(pf, vf, acc_o[nj], 0, 0, 0);
        }
      }
      __builtin_amdgcn_s_setprio(0);

      asm volatile("" ::: "memory");
      __builtin_amdgcn_s_barrier();   // all waves done reading buf[cur] before re-stage
      cur ^= 1;
    }

    // fused expand_o epilogue: Ae[token][(h*4+e)*128 + dh] = (o / l) * gate_o[token][h][e]
    #pragma unroll
    for (int r = 0; r < 4; r++) {
      int s = qt * 64 + wave * 16 + quad * 4 + r;
      int token = b * 2048 + s;
      float4 g4 = *(const float4*)(gate_o + ((size_t)token * 8 + h) * 4);
      float inv = 1.0f / l_run[r];
      #pragma unroll
      for (int nj = 0; nj < 8; nj++) {
        float o = acc_o[nj][r] * inv;
        bf16* dst = Ae + (size_t)token * 4096 + (h * 4) * 128 + nj * 16 + l16;
        dst[0]   = (bf16)(o * g4.x);
        dst[128] = (bf16)(o * g4.y);
        dst[256] = (bf16)(o * g4.z);
        dst[384] = (bf16)(o * g4.w);
      }
    }
  }
}

// ---------------- launch ----------------
extern "C" void kernel_launch(void* const* d_in, const int* in_sizes, int n_in,
                              void* d_out, int out_size, void* d_ws, size_t ws_size,
                              hipStream_t stream) {
  const float* q_src  = (const float*)d_in[0];
  const float* k_src  = (const float*)d_in[1];
  const float* v_src  = (const float*)d_in[2];
  const float* wq     = (const float*)d_in[3];
  const float* wk     = (const float*)d_in[4];
  const float* sel_v_w = (const float*)d_in[5];
  const float* sel_o_w = (const float*)d_in[6];
  const float* v_w    = (const float*)d_in[7];
  const float* o_w    = (const float*)d_in[8];
  const float* bias_v = (const float*)d_in[9];
  const float* bias_o = (const float*)d_in[10];
  float* out = (float*)d_out;

  char* ws = (char*)d_ws;
  size_t off = 0;
  auto alloc = [&](size_t bytes) { char* p = ws + off; off += (bytes + 255) & ~(size_t)255; return p; };
  bf16* wqb   = (bf16*)alloc((size_t)1024 * 1024 * 2);
  bf16* wkb   = (bf16*)alloc((size_t)1024 * 1024 * 2);
  bf16* wvt   = (bf16*)alloc((size_t)8 * 128 * 4 * 1024 * 2);
  bf16* wot   = (bf16*)alloc((size_t)1024 * 4096 * 2);
  float* gate_v = (float*)alloc((size_t)8192 * 32 * 4);
  float* gate_o = (float*)alloc((size_t)8192 * 32 * 4);
  // Ae (8192 x 4096 bf16 = 64 MB) overlays qsb+ksb+vsb+pad — all dead when attn runs
  // (qsb/ksb consumed by fused gemm0, vsb by gemm1; qb/kb/vbT live AFTER this span).
  bf16* qsb   = (bf16*)alloc((size_t)8192 * 1024 * 2);   // bf16 copies of srcs
  bf16* ksb   = (bf16*)alloc((size_t)8192 * 1024 * 2);
  bf16* vsb   = (bf16*)alloc((size_t)8192 * 1024 * 2);
  (void)alloc((size_t)8192 * 1024 * 2);                  // pad to complete Ae's 64 MB
  bf16* Ae    = qsb;
  bf16* qb    = (bf16*)alloc((size_t)8192 * 1024 * 2);   // [b,h,s,dh]
  bf16* kb    = (bf16*)alloc((size_t)8192 * 1024 * 2);   // [b,h,s,dh]
  bf16* vbT   = (bf16*)alloc((size_t)8192 * 1024 * 2);   // [b,h,dh,s]

  cvt_all<<<dim3(8192, 5), 256, 0, stream>>>((const float4*)q_src, (const float4*)k_src,
                                             (const float4*)v_src, (const float4*)wq,
                                             (const float4*)wk, (bf16x4*)qsb, (bf16x4*)ksb,
                                             (bf16x4*)vsb, (bf16x4*)wqb, (bf16x4*)wkb);
  make_w<<<dim3(16, 2, 64), 256, 0, stream>>>(v_w, o_w, wvt, wot);
  gating<<<dim3(128, 2), 256, 0, stream>>>(q_src, k_src, sel_v_w, sel_o_w,
                                           bias_v, bias_o, gate_v, gate_o, out);

  const float ssq = 0.29730177875068026f;            // 128^-0.25 (applied to both q and k)
  const float log2e = 1.4426950408889634f;
  // fused Q/K projection: blocks 0-255 -> Q (scale incl. log2e), 256-511 -> K
  gemm_moe<0><<<512, 512, 0, stream>>>(qsb, wqb, nullptr, qb, nullptr, ssq * log2e,
                                       ksb, wkb, kb, ssq);
  gemm_moe<1><<<256, 512, 0, stream>>>(vsb, wvt, gate_v, vbT, nullptr, 1.0f,
                                       nullptr, nullptr, nullptr, 0.f);
  attn_kernel<<<dim3(16, 32), 256, 0, stream>>>(qb, kb, vbT, gate_o, Ae);
  gemm_moe<2><<<256, 512, 0, stream>>>(Ae, wot, nullptr, nullptr, out, 1.0f,
                                       nullptr, nullptr, nullptr, 0.f);
}

// Round 10
// 561.571 us; speedup vs baseline: 1.0929x; 1.0087x over previous
//
#include <hip/hip_runtime.h>
#include <cstdint>
#include <cstddef>

typedef __bf16 bf16;
typedef __bf16 bf16x4 __attribute__((ext_vector_type(4)));
typedef __bf16 bf16x8 __attribute__((ext_vector_type(8)));
typedef float  fx4    __attribute__((ext_vector_type(4)));

// Problem dims (fixed): B=4, S=2048, D=1024, H=8, E=4, DH=128, K_route=2

// async global->LDS DMA, 16 B per lane; dest = wave-uniform base + lane*16 (m97/m104)
__device__ __forceinline__ void async16(const void* g, void* l) {
  __builtin_amdgcn_global_load_lds((const __attribute__((address_space(1))) void*)g,
                                   (__attribute__((address_space(3))) void*)l, 16, 0, 0);
}

#define BARRIER() do { asm volatile("" ::: "memory"); __builtin_amdgcn_s_barrier(); \
                       asm volatile("" ::: "memory"); } while (0)

// DPP row-rotate (within 16-lane rows) — VALU-pipe cross-lane reduce (vs ds_bpermute).
template <int CTRL>
__device__ __forceinline__ float dppf(float x) {
  return __int_as_float(__builtin_amdgcn_update_dpp(
      0, __float_as_int(x), CTRL, 0xf, 0xf, true));
}

// ---------------- fused f32 -> bf16 for all 5 tensors (1 launch, G13-vectorized) -------
__global__ __launch_bounds__(256) void cvt_all(const float4* __restrict__ q,
                                               const float4* __restrict__ k,
                                               const float4* __restrict__ v,
                                               const float4* __restrict__ wq,
                                               const float4* __restrict__ wk,
                                               bf16x4* __restrict__ qo, bf16x4* __restrict__ ko,
                                               bf16x4* __restrict__ vo, bf16x4* __restrict__ wqo,
                                               bf16x4* __restrict__ wko) {
  const int y = blockIdx.y;
  const float4* s; bf16x4* d; int n4;
  if      (y == 0) { s = q;  d = qo;  n4 = 2097152; }
  else if (y == 1) { s = k;  d = ko;  n4 = 2097152; }
  else if (y == 2) { s = v;  d = vo;  n4 = 2097152; }
  else if (y == 3) { s = wq; d = wqo; n4 = 262144; }
  else             { s = wk; d = wko; n4 = 262144; }
  int i = blockIdx.x * 256 + threadIdx.x;
  if (i < n4) {
    float4 t = s[i];
    bf16x4 o;
    o[0] = (bf16)t.x; o[1] = (bf16)t.y; o[2] = (bf16)t.z; o[3] = (bf16)t.w;
    d[i] = o;
  }
}

// fused weight transposes (1 launch): z<32 -> wvt, z>=32 -> wot
// wvt[h][dh][e][k] <- v_w[h][e][k][dh];  wot[d][h][e][dh] <- o_w[h][e][dh][d]
__global__ __launch_bounds__(256) void make_w(const float* __restrict__ v_w,
                                              const float* __restrict__ o_w,
                                              bf16* __restrict__ wvt,
                                              bf16* __restrict__ wot) {
  __shared__ float tile[64][65];
  if (blockIdx.z < 32) {
    const int he = blockIdx.z, k0 = blockIdx.x * 64, dh0 = blockIdx.y * 64;
    const float* in = v_w + (size_t)he * 1024 * 128;
    #pragma unroll
    for (int j = 0; j < 16; j++) {
      int idx = threadIdx.x + j * 256;
      int r = idx >> 6, c = idx & 63;                 // r=k, c=dh
      tile[r][c] = in[(size_t)(k0 + r) * 128 + dh0 + c];
    }
    __syncthreads();
    const int h = he >> 2, e = he & 3;
    bf16* outp = wvt + ((size_t)(h * 128 + dh0) * 4 + e) * 1024 + k0;
    #pragma unroll
    for (int j = 0; j < 16; j++) {
      int idx = threadIdx.x + j * 256;
      int r = idx >> 6, c = idx & 63;                 // r=dh, c=k
      outp[(size_t)r * 4096 + c] = (bf16)tile[c][r];
    }
  } else {
    const int he = blockIdx.z - 32, d0 = blockIdx.x * 64, dh0 = blockIdx.y * 64;
    const float* in = o_w + (size_t)he * 128 * 1024;
    #pragma unroll
    for (int j = 0; j < 16; j++) {
      int idx = threadIdx.x + j * 256;
      int r = idx >> 6, c = idx & 63;                 // r=dh, c=d
      tile[r][c] = in[(size_t)(dh0 + r) * 1024 + d0 + c];
    }
    __syncthreads();
    bf16* outp = wot + (size_t)d0 * 4096 + he * 128 + dh0;
    #pragma unroll
    for (int j = 0; j < 16; j++) {
      int idx = threadIdx.x + j * 256;
      int r = idx >> 6, c = idx & 63;                 // r=d, c=dh
      outp[(size_t)r * 4096 + c] = (bf16)tile[c][r];
    }
  }
}

// ---------------- gating (R6): register-blocked LDS-staged mini-GEMM ----------------
__global__ __launch_bounds__(256) void gating(const float* __restrict__ q_src,
                                              const float* __restrict__ k_src,
                                              const float* __restrict__ sel_v_w,
                                              const float* __restrict__ sel_o_w,
                                              const float* __restrict__ bias_v,
                                              const float* __restrict__ bias_o,
                                              float* __restrict__ gate_v,
                                              float* __restrict__ gate_o,
                                              float* __restrict__ d_out) {
  const int g = blockIdx.y;
  const int m0 = blockIdx.x * 64;
  const float* x = g ? q_src : k_src;
  const float* w = g ? sel_o_w : sel_v_w;
  const float* bias = g ? bias_o : bias_v;
  float* gate = g ? gate_o : gate_v;
  float* idxo = d_out + 8388608 + g * 131072;       // v_idx then o_idx, as float values

  // [buf][ xs 64x128 f32 | ws 32x128 f32 ] = 2 x 48 KB
  __shared__ __align__(16) float smem[2 * 12288];

  const int t = threadIdx.x;
  const int hg = t & 7;          // head
  const int tg = t >> 3;         // token pair 0..31

  auto stage = [&](int buf, int k0) {
    float* xs = smem + buf * 12288;
    float* ws = xs + 8192;
    #pragma unroll
    for (int p = 0; p < 8; p++) {                    // xs: 64 rows x 128 f32
      int of = p * 1024 + t * 4;
      int row = of >> 7, c = (of >> 2) & 31;
      int sc = c ^ ((row >> 1) & 7);                 // pre-swizzled source chunk
      async16(x + (size_t)(m0 + row) * 1024 + k0 + sc * 4, xs + of);
    }
    #pragma unroll
    for (int p = 0; p < 4; p++) {                    // ws: 32 rows x 128 f32
      int of = p * 1024 + t * 4;
      int row = of >> 7, c = (of >> 2) & 31;
      int sc = c ^ ((row >> 2) & 7);
      async16(w + (size_t)row * 1024 + k0 + sc * 4, ws + of);
    }
  };

  double acc[2][4] = {};

  stage(0, 0);
  int buf = 0;
  for (int c8 = 0; c8 < 8; c8++) {
    if (c8 < 7) {
      stage(buf ^ 1, (c8 + 1) * 128);                  // prefetch next chunk
      asm volatile("s_waitcnt vmcnt(12)" ::: "memory"); // wait current chunk only
    } else {
      asm volatile("s_waitcnt vmcnt(0)" ::: "memory");
    }
    BARRIER();
    const float* xs = smem + buf * 12288;
    const float* ws = xs + 8192;
    const int xr0 = tg * 2;
    #pragma unroll 4
    for (int k4 = 0; k4 < 32; k4++) {
      float4 x0 = *(const float4*)(xs + (size_t)xr0 * 128 + (size_t)((k4 ^ (tg & 7)) * 4));
      float4 x1 = *(const float4*)(xs + (size_t)(xr0 + 1) * 128 + (size_t)((k4 ^ (tg & 7)) * 4));
      double x0d[4] = {(double)x0.x, (double)x0.y, (double)x0.z, (double)x0.w};
      double x1d[4] = {(double)x1.x, (double)x1.y, (double)x1.z, (double)x1.w};
      #pragma unroll
      for (int e = 0; e < 4; e++) {
        int wr = hg * 4 + e;
        float4 wv = *(const float4*)(ws + (size_t)wr * 128 + (size_t)((k4 ^ hg) * 4));
        double w0 = (double)wv.x, w1 = (double)wv.y, w2 = (double)wv.z, w3 = (double)wv.w;
        acc[0][e] += x0d[0] * w0 + x0d[1] * w1 + x0d[2] * w2 + x0d[3] * w3;
        acc[1][e] += x1d[0] * w0 + x1d[1] * w1 + x1d[2] * w2 + x1d[3] * w3;
      }
    }
    BARRIER();   // all waves done with buf before it is re-staged next iteration
    buf ^= 1;
  }

  const float log2e = 1.4426950408889634f;
  float b0 = bias[0], b1 = bias[1], b2 = bias[2], b3 = bias[3];
  #pragma unroll
  for (int tok = 0; tok < 2; tok++) {
    int m = m0 + tg * 2 + tok;
    float sel[4];
    #pragma unroll
    for (int e = 0; e < 4; e++) {
      float lv = (float)acc[tok][e];
      sel[e] = 1.0f / (1.0f + __builtin_amdgcn_exp2f(-lv * log2e));
    }
    float vb[4] = {sel[0] + b0, sel[1] + b1, sel[2] + b2, sel[3] + b3};
    int i0 = 0;
    #pragma unroll
    for (int e = 1; e < 4; e++) if (vb[e] > vb[i0]) i0 = e;
    int i1 = -1; float best = -1e30f;
    #pragma unroll
    for (int e = 0; e < 4; e++) { if (e == i0) continue; if (vb[e] > best) { best = vb[e]; i1 = e; } }
    float4 gv;
    gv.x = (i0 == 0 || i1 == 0) ? sel[0] : 0.f;
    gv.y = (i0 == 1 || i1 == 1) ? sel[1] : 0.f;
    gv.z = (i0 == 2 || i1 == 2) ? sel[2] : 0.f;
    gv.w = (i0 == 3 || i1 == 3) ? sel[3] : 0.f;
    *(float4*)(gate + ((size_t)m * 8 + hg) * 4) = gv;
    idxo[m * 16 + hg * 2 + 0] = (float)i0;
    idxo[m * 16 + hg * 2 + 1] = (float)i1;
  }
}

// ---------------- GEMM: C[M x N] = A @ BT^T, bf16 MFMA 16x16x32 ----------------
// R5 structure: 256x128 tile, 8 waves, BK=64, dbuf 96 KB LDS, counted vmcnt(6), phase-split
// MFMA with setprio, T2 swizzle. R8: MODE 0 fuses Q and K GEMMs (bid>>8 selects set).
// R10 (T1, XCD-model fix): R9's bid%8-based remap produced BYTE-IDENTICAL FETCH (282 MB)
// -> XCD assignment is NOT bid%8. attn's working remap used stride-32 congruence; the
// consistent model is XCD = (bid>>2)%8 (granularity-4 round-robin; 4 SEs/XCD). Robust
// mapping for modes 0/2: mt = lbid&31, np = lbid>>5 — same-mt blocks (the 8 sharing one
// A-tile) sit at bid stride 32 = same XCD under ANY round-robin with period | 32.
// Per XCD: 4 m-tiles (2 MB) + B (2 MB) = L2-resident. MODE 1 unchanged.
template <int MODE>
__global__ __launch_bounds__(512) void gemm_moe(const bf16* __restrict__ Abf,
                                                const bf16* __restrict__ BT,
                                                const float* __restrict__ gate,
                                                bf16* __restrict__ Cbf,
                                                float* __restrict__ Cf32,
                                                float scale,
                                                const bf16* __restrict__ Abf2,
                                                const bf16* __restrict__ BT2,
                                                bf16* __restrict__ Cbf2,
                                                float scale2) {
  constexpr int KDIM = (MODE == 0) ? 1024 : 4096;
  constexpr int ASTRIDE = (MODE == 2) ? 4096 : 1024;
  __shared__ __align__(16) bf16 smem[49152];   // [2][A 256x64] + [2][B 128x64] = 96 KB
  const int t = threadIdx.x;
  const int wave = t >> 6, lane = t & 63;
  const int wr = wave >> 1, wc = wave & 1;          // 4 M-groups x 2 N-groups
  const int quad = lane >> 4, l16 = lane & 15;
  const int bid = blockIdx.x;
  const int sel = (MODE == 0) ? (bid >> 8) : 0;
  const bf16* A  = sel ? Abf2 : Abf;
  const bf16* Bt = sel ? BT2  : BT;
  bf16* Cb       = sel ? Cbf2 : Cbf;
  const float scl = sel ? scale2 : scale;
  const int lbid = (MODE == 0) ? (bid & 255) : bid;
  // R10 remap: same-mt blocks at bid stride 32 (XCD-invariant colocation).
  const int mt = (MODE == 1) ? (lbid >> 3) : (lbid & 31);
  const int np = (MODE == 1) ? (lbid & 7) : (lbid >> 5);
  const int m0 = mt * 256;
  const int n0 = (MODE == 1) ? 0 : np * 128;
  const int h = (MODE == 1) ? np : 0;
  const bf16* BTh = (MODE == 1) ? Bt + (size_t)h * 128 * 4096 : Bt;

  fx4 acc[4][4] = {};    // per-wave 64x64 output (4 mi x 4 ni)
  fx4 accT[4][4] = {};   // gated total (mode 1 only; DCE'd otherwise)

  const int srow = t >> 3, sch = t & 7;   // staging: 64 rows x 8 chunks (16 B) per pass

  auto stage = [&](int buf, int k0) {
    bf16* As = smem + buf * 16384;
    bf16* Bs = smem + 32768 + buf * 8192;
    #pragma unroll
    for (int p = 0; p < 2; p++) {                    // B: 128 rows
      int row = p * 64 + srow;
      int sc = sch ^ (row & 7);
      async16(BTh + (size_t)(n0 + row) * KDIM + k0 + sc * 8,
              Bs + row * 64 + sch * 8);
    }
    int col = (MODE == 1) ? (k0 & 1023) : k0;
    #pragma unroll
    for (int p = 0; p < 4; p++) {                    // A: 256 rows
      int row = p * 64 + srow;
      int sc = sch ^ (row & 7);
      async16(A + (size_t)(m0 + row) * ASTRIDE + col + sc * 8,
              As + row * 64 + sch * 8);
    }
  };

  stage(0, 0);
  int buf = 0;
  for (int k0 = 0; k0 < KDIM; k0 += 64) {
    if (k0 + 64 < KDIM) {
      stage(buf ^ 1, k0 + 64);                         // prefetch next K-tile
      asm volatile("s_waitcnt vmcnt(6)" ::: "memory"); // wait current tile only
    } else {
      asm volatile("s_waitcnt vmcnt(0)" ::: "memory");
    }
    BARRIER();
    const bf16* As = smem + buf * 16384;
    const bf16* Bs = smem + 32768 + buf * 8192;
    #pragma unroll
    for (int kk = 0; kk < 64; kk += 32) {
      bf16x8 af[4], bfr[4];
      // phase A: A-frags + B-frags ni 0,1
      #pragma unroll
      for (int i = 0; i < 4; i++) {
        int ar = wr * 64 + i * 16 + l16;
        af[i] = *(const bf16x8*)(As + ar * 64 + ((((kk >> 3) + quad) ^ (ar & 7)) * 8));
      }
      #pragma unroll
      for (int i = 0; i < 2; i++) {
        int br = wc * 64 + i * 16 + l16;
        bfr[i] = *(const bf16x8*)(Bs + br * 64 + ((((kk >> 3) + quad) ^ (br & 7)) * 8));
      }
      BARRIER();
      __builtin_amdgcn_s_setprio(1);
      #pragma unroll
      for (int mi = 0; mi < 4; mi++)
        #pragma unroll
        for (int ni = 0; ni < 2; ni++)
          acc[mi][ni] = __builtin_amdgcn_mfma_f32_16x16x32_bf16(af[mi], bfr[ni], acc[mi][ni], 0, 0, 0);
      __builtin_amdgcn_s_setprio(0);
      BARRIER();
      // phase B: B-frags ni 2,3 (af held in regs)
      #pragma unroll
      for (int i = 2; i < 4; i++) {
        int br = wc * 64 + i * 16 + l16;
        bfr[i] = *(const bf16x8*)(Bs + br * 64 + ((((kk >> 3) + quad) ^ (br & 7)) * 8));
      }
      BARRIER();
      __builtin_amdgcn_s_setprio(1);
      #pragma unroll
      for (int mi = 0; mi < 4; mi++)
        #pragma unroll
        for (int ni = 2; ni < 4; ni++)
          acc[mi][ni] = __builtin_amdgcn_mfma_f32_16x16x32_bf16(af[mi], bfr[ni], acc[mi][ni], 0, 0, 0);
      __builtin_amdgcn_s_setprio(0);
      BARRIER();
    }
    if constexpr (MODE == 1) {
      if (((k0 + 64) & 1023) == 0) {     // expert-chunk boundary: 4 merges total
        const int e = k0 >> 10;
        #pragma unroll
        for (int mi = 0; mi < 4; mi++)
          #pragma unroll
          for (int r = 0; r < 4; r++) {
            int m = m0 + wr * 64 + mi * 16 + quad * 4 + r;
            float gv = gate[((size_t)m * 8 + h) * 4 + e];
            #pragma unroll
            for (int ni = 0; ni < 4; ni++)
              accT[mi][ni][r] += gv * acc[mi][ni][r];
          }
        #pragma unroll
        for (int mi = 0; mi < 4; mi++)
          #pragma unroll
          for (int ni = 0; ni < 4; ni++)
            #pragma unroll
            for (int j = 0; j < 4; j++) acc[mi][ni][j] = 0.f;
      }
    }
    buf ^= 1;
  }

  if (MODE == 1) {
    // transpose through LDS -> vbT[b,h,dh,s] with coalesced global writes
    #pragma unroll
    for (int mi = 0; mi < 4; mi++)
      #pragma unroll
      for (int ni = 0; ni < 4; ni++) {
        int nl = wc * 64 + ni * 16 + l16;
        int ml = wr * 64 + mi * 16 + quad * 4;
        bf16x4 pk;
        #pragma unroll
        for (int r = 0; r < 4; r++) pk[r] = (bf16)accT[mi][ni][r];
        *(bf16x4*)(smem + nl * 264 + ml) = pk;
      }
    __syncthreads();
    int b = m0 >> 11, s0 = m0 & 2047;
    const int row = t >> 2, seg = t & 3;
    bf16* dst = Cb + (((size_t)(b * 8 + h) * 128) + row) * 2048 + s0 + seg * 64;
    #pragma unroll
    for (int j = 0; j < 8; j++)
      *(float4*)(dst + j * 8) = *(float4*)(smem + row * 264 + seg * 64 + j * 8);
    return;
  }

  // epilogue: C/D layout col=lane&15, row=quad*4+reg
  #pragma unroll
  for (int mi = 0; mi < 4; mi++)
    #pragma unroll
    for (int ni = 0; ni < 4; ni++)
      #pragma unroll
      for (int r = 0; r < 4; r++) {
        int m = m0 + wr * 64 + mi * 16 + quad * 4 + r;
        int n = n0 + wc * 64 + ni * 16 + l16;
        float v = acc[mi][ni][r] * scl;
        if (MODE == 0) {
          int b = m >> 11, s = m & 2047, hh = n >> 7, dh = n & 127;
          Cb[(((size_t)(b * 8 + hh) * 2048 + s) << 7) + dh] = (bf16)v;
        } else {
          Cf32[(size_t)m * 1024 + n] = v;
        }
      }
}

// ---------------- flash attention (causal) ----------------
// R8 = R6 4-wave structure + XCD-cluster remap (FETCH 194->29 MB; stride-32 congruence)
// + T13 defer-max + fused expand_o epilogue. R9 counters: dur 94.2, VALU 45.6%, occ 19.6%.
__global__ __launch_bounds__(256) void attn_kernel(const bf16* __restrict__ qb,
                                                   const bf16* __restrict__ kb,
                                                   const bf16* __restrict__ vbT,
                                                   const float* __restrict__ gate_o,
                                                   bf16* __restrict__ Ae) {
  // XCD-clustering remap: all 16 pair-blocks of one bh at stride 32 -> one XCD.
  const int linear = blockIdx.y * 16 + blockIdx.x;
  const int bh = (linear & 7) * 4 + ((linear >> 3) & 3);
  const int px = linear >> 5;                      // pair index 0..15
  const int b = bh >> 3, h = bh & 7;
  __shared__ __align__(16) bf16 Ks[2][64 * 128];    // [buf][k-row * 128 + dh], swizzled
  __shared__ __align__(16) bf16 VTs[2][128 * 64];   // [buf][dh-row * 64 + s], swizzled
  __shared__ __align__(16) bf16 Ps[4][16][72];
  const int t = threadIdx.x, wave = t >> 6, lane = t & 63;
  const int quad = lane >> 4, l16 = lane & 15;
  const bf16* qbase  = qb  + (size_t)bh * 2048 * 128;
  const bf16* kbase  = kb  + (size_t)bh * 2048 * 128;
  const bf16* vtbase = vbT + (size_t)bh * 128 * 2048;

  auto stage = [&](int buf, int kt) {
    #pragma unroll
    for (int p = 0; p < 4; p++) {
      int o = p * 4096 + wave * 1024 + lane * 16;        // byte offset in 16 KiB tile
      int kr = o >> 8, kc = o & 255;                     // 256 B rows (128 bf16)
      async16((const char*)kbase + (size_t)(kt * 64 + kr) * 256 + (kc ^ ((kr & 7) << 4)),
              (char*)&Ks[buf][0] + o);
    }
    #pragma unroll
    for (int p = 0; p < 4; p++) {
      int o = p * 4096 + wave * 1024 + lane * 16;
      int vr = o >> 7, vc = o & 127;                     // 128 B rows (64 bf16)
      async16((const char*)vtbase + (size_t)vr * 4096 + kt * 128 + (vc ^ ((vr & 7) << 4)),
              (char*)&VTs[buf][0] + o);
    }
  };

  #pragma unroll 1
  for (int pass = 0; pass < 2; pass++) {
    const int qt = pass ? px : (31 - px);                // heavy tile first

    bf16x8 qf[4];
    #pragma unroll
    for (int dk = 0; dk < 4; dk++)
      qf[dk] = *(const bf16x8*)(qbase + (size_t)(qt * 64 + wave * 16 + l16) * 128 + dk * 32 + quad * 8);

    float m_run[4], l_run[4];
    fx4 acc_o[8] = {};
    #pragma unroll
    for (int r = 0; r < 4; r++) { m_run[r] = -1e30f; l_run[r] = 0.f; }

    stage(0, 0);
    int cur = 0;

    for (int kt = 0; kt <= qt; kt++) {
      if (kt < qt) {
        stage(cur ^ 1, kt + 1);                            // prefetch next tile
        asm volatile("s_waitcnt vmcnt(8)" ::: "memory");   // wait tile kt only
      } else {
        asm volatile("s_waitcnt vmcnt(0)" ::: "memory");
      }
      __builtin_amdgcn_s_barrier();
      asm volatile("" ::: "memory");

      const char* Ksb  = (const char*)&Ks[cur][0];
      const char* VTsb = (const char*)&VTs[cur][0];

      fx4 accs[4] = {};
      __builtin_amdgcn_s_setprio(1);
      #pragma unroll
      for (int ni = 0; ni < 4; ni++)
        #pragma unroll
        for (int dk = 0; dk < 4; dk++) {
          int r = ni * 16 + l16;
          bf16x8 kf = *(const bf16x8*)(Ksb + r * 256 + ((dk * 64 + quad * 16) ^ ((r & 7) << 4)));
          accs[ni] = __builtin_amdgcn_mfma_f32_16x16x32_bf16(qf[dk], kf, accs[ni], 0, 0, 0);
        }
      __builtin_amdgcn_s_setprio(0);

      if (kt == qt) {   // causal mask on the diagonal tile
        #pragma unroll
        for (int ni = 0; ni < 4; ni++)
          #pragma unroll
          for (int r = 0; r < 4; r++) {
            int qr = wave * 16 + quad * 4 + r;
            int kc = ni * 16 + l16;
            if (kc > qr) accs[ni][r] = -1e30f;
          }
      }

      // softmax in exp2 domain; DPP row_ror reductions; T13 defer-max
      float mxv[4];
      #pragma unroll
      for (int r = 0; r < 4; r++) {
        float mx = fmaxf(fmaxf(accs[0][r], accs[1][r]), fmaxf(accs[2][r], accs[3][r]));
        mx = fmaxf(mx, dppf<0x121>(mx));
        mx = fmaxf(mx, dppf<0x122>(mx));
        mx = fmaxf(mx, dppf<0x124>(mx));
        mx = fmaxf(mx, dppf<0x128>(mx));
        mxv[r] = mx;
      }
      bool defer = (mxv[0] <= m_run[0] + 8.f) && (mxv[1] <= m_run[1] + 8.f) &&
                   (mxv[2] <= m_run[2] + 8.f) && (mxv[3] <= m_run[3] + 8.f);
      if (__all(defer)) {
        // keep old max: P bounded by 2^8, no acc_o rescale, no alpha
        #pragma unroll
        for (int r = 0; r < 4; r++) {
          float rs = 0.f;
          #pragma unroll
          for (int ni = 0; ni < 4; ni++) {
            float p = __builtin_amdgcn_exp2f(accs[ni][r] - m_run[r]);
            accs[ni][r] = p; rs += p;
          }
          rs += dppf<0x121>(rs);
          rs += dppf<0x122>(rs);
          rs += dppf<0x124>(rs);
          rs += dppf<0x128>(rs);
          l_run[r] += rs;
        }
      } else {
        #pragma unroll
        for (int r = 0; r < 4; r++) {
          float m_new = fmaxf(m_run[r], mxv[r]);
          float alpha = __builtin_amdgcn_exp2f(m_run[r] - m_new);
          float rs = 0.f;
          #pragma unroll
          for (int ni = 0; ni < 4; ni++) {
            float p = __builtin_amdgcn_exp2f(accs[ni][r] - m_new);
            accs[ni][r] = p; rs += p;
          }
          rs += dppf<0x121>(rs);
          rs += dppf<0x122>(rs);
          rs += dppf<0x124>(rs);
          rs += dppf<0x128>(rs);
          l_run[r] = l_run[r] * alpha + rs;
          m_run[r] = m_new;
          #pragma unroll
          for (int nj = 0; nj < 8; nj++) acc_o[nj][r] *= alpha;
        }
      }

      // P: C-layout -> LDS -> A-layout (per-wave region; DS in-order within a wave)
      #pragma unroll
      for (int ni = 0; ni < 4; ni++)
        #pragma unroll
        for (int r = 0; r < 4; r++)
          Ps[wave][quad * 4 + r][ni * 16 + l16] = (bf16)accs[ni][r];

      __builtin_amdgcn_s_setprio(1);
      #pragma unroll
      for (int step = 0; step < 2; step++) {
        bf16x8 pf = *(const bf16x8*)&Ps[wave][l16][step * 32 + quad * 8];
        #pragma unroll
        for (int nj = 0; nj < 8; nj++) {
          int r = nj * 16 + l16;
          bf16x8 vf = *(const bf16x8*)(VTsb + r * 128 + ((step * 64 + quad * 16) ^ ((r & 7) << 4)));
          acc_o[nj] = __builtin_amdgcn_mfma_f32_16x16x32_bf16(pf, vf, acc_o[nj], 0, 0, 0);
        }
      }
      __builtin_amdgcn_s_setprio(0);

      asm volatile("" ::: "memory");
      __builtin_amdgcn_s_barrier();   // all waves done reading buf[cur] before re-stage
      cur ^= 1;
    }

    // fused expand_o epilogue: Ae[token][(h*4+e)*128 + dh] = (o / l) * gate_o[token][h][e]
    #pragma unroll
    for (int r = 0; r < 4; r++) {
      int s = qt * 64 + wave * 16 + quad * 4 + r;
      int token = b * 2048 + s;
      float4 g4 = *(const float4*)(gate_o + ((size_t)token * 8 + h) * 4);
      float inv = 1.0f / l_run[r];
      #pragma unroll
      for (int nj = 0; nj < 8; nj++) {
        float o = acc_o[nj][r] * inv;
        bf16* dst = Ae + (size_t)token * 4096 + (h * 4) * 128 + nj * 16 + l16;
        dst[0]   = (bf16)(o * g4.x);
        dst[128] = (bf16)(o * g4.y);
        dst[256] = (bf16)(o * g4.z);
        dst[384] = (bf16)(o * g4.w);
      }
    }
  }
}

// ---------------- launch ----------------
extern "C" void kernel_launch(void* const* d_in, const int* in_sizes, int n_in,
                              void* d_out, int out_size, void* d_ws, size_t ws_size,
                              hipStream_t stream) {
  const float* q_src  = (const float*)d_in[0];
  const float* k_src  = (const float*)d_in[1];
  const float* v_src  = (const float*)d_in[2];
  const float* wq     = (const float*)d_in[3];
  const float* wk     = (const float*)d_in[4];
  const float* sel_v_w = (const float*)d_in[5];
  const float* sel_o_w = (const float*)d_in[6];
  const float* v_w    = (const float*)d_in[7];
  const float* o_w    = (const float*)d_in[8];
  const float* bias_v = (const float*)d_in[9];
  const float* bias_o = (const float*)d_in[10];
  float* out = (float*)d_out;

  char* ws = (char*)d_ws;
  size_t off = 0;
  auto alloc = [&](size_t bytes) { char* p = ws + off; off += (bytes + 255) & ~(size_t)255; return p; };
  bf16* wqb   = (bf16*)alloc((size_t)1024 * 1024 * 2);
  bf16* wkb   = (bf16*)alloc((size_t)1024 * 1024 * 2);
  bf16* wvt   = (bf16*)alloc((size_t)8 * 128 * 4 * 1024 * 2);
  bf16* wot   = (bf16*)alloc((size_t)1024 * 4096 * 2);
  float* gate_v = (float*)alloc((size_t)8192 * 32 * 4);
  float* gate_o = (float*)alloc((size_t)8192 * 32 * 4);
  // Ae (8192 x 4096 bf16 = 64 MB) overlays qsb+ksb+vsb+pad — all dead when attn runs
  // (qsb/ksb consumed by fused gemm0, vsb by gemm1; qb/kb/vbT live AFTER this span).
  bf16* qsb   = (bf16*)alloc((size_t)8192 * 1024 * 2);   // bf16 copies of srcs
  bf16* ksb   = (bf16*)alloc((size_t)8192 * 1024 * 2);
  bf16* vsb   = (bf16*)alloc((size_t)8192 * 1024 * 2);
  (void)alloc((size_t)8192 * 1024 * 2);                  // pad to complete Ae's 64 MB
  bf16* Ae    = qsb;
  bf16* qb    = (bf16*)alloc((size_t)8192 * 1024 * 2);   // [b,h,s,dh]
  bf16* kb    = (bf16*)alloc((size_t)8192 * 1024 * 2);   // [b,h,s,dh]
  bf16* vbT   = (bf16*)alloc((size_t)8192 * 1024 * 2);   // [b,h,dh,s]

  cvt_all<<<dim3(8192, 5), 256, 0, stream>>>((const float4*)q_src, (const float4*)k_src,
                                             (const float4*)v_src, (const float4*)wq,
                                             (const float4*)wk, (bf16x4*)qsb, (bf16x4*)ksb,
                                             (bf16x4*)vsb, (bf16x4*)wqb, (bf16x4*)wkb);
  make_w<<<dim3(16, 2, 64), 256, 0, stream>>>(v_w, o_w, wvt, wot);
  gating<<<dim3(128, 2), 256, 0, stream>>>(q_src, k_src, sel_v_w, sel_o_w,
                                           bias_v, bias_o, gate_v, gate_o, out);

  const float ssq = 0.29730177875068026f;            // 128^-0.25 (applied to both q and k)
  const float log2e = 1.4426950408889634f;
  // fused Q/K projection: blocks 0-255 -> Q (scale incl. log2e), 256-511 -> K
  gemm_moe<0><<<512, 512, 0, stream>>>(qsb, wqb, nullptr, qb, nullptr, ssq * log2e,
                                       ksb, wkb, kb, ssq);
  gemm_moe<1><<<256, 512, 0, stream>>>(vsb, wvt, gate_v, vbT, nullptr, 1.0f,
                                       nullptr, nullptr, nullptr, 0.f);
  attn_kernel<<<dim3(16, 32), 256, 0, stream>>>(qb, kb, vbT, gate_o, Ae);
  gemm_moe<2><<<256, 512, 0, stream>>>(Ae, wot, nullptr, nullptr, out, 1.0f,
                                       nullptr, nullptr, nullptr, 0.f);
}